// Round 1
// baseline (940.709 us; speedup 1.0000x reference)
//
#include <hip/hip_runtime.h>

#define N_NODES 50000
#define N_ADJ 6
#define NNZ 800000
#define D_PREV 256
#define D_HID 128
#define LN_EPS 1e-5f

static constexpr int HIST_EPT = 8;
static constexpr int HIST_BLOCK = 256;
static constexpr int BPA = (NNZ + HIST_BLOCK * HIST_EPT - 1) / (HIST_BLOCK * HIST_EPT); // 391

static constexpr size_t align256(size_t x) { return (x + 255) & ~(size_t)255; }
static constexpr size_t USED_OFF   = 0;
static constexpr size_t ROWPTR_OFF = align256(USED_OFF + N_ADJ * sizeof(int));
static constexpr size_t CURSOR_OFF = align256(ROWPTR_OFF + (size_t)N_ADJ * (N_NODES + 1) * sizeof(int));
static constexpr size_t SCOLS_OFF  = align256(CURSOR_OFF + (size_t)N_ADJ * N_NODES * sizeof(int));
static constexpr size_t SVALS_OFF  = align256(SCOLS_OFF + (size_t)N_ADJ * NNZ * sizeof(int));
static constexpr size_t H_OFF      = align256(SVALS_OFF + (size_t)N_ADJ * NNZ * sizeof(float));
static constexpr size_t S1_OFF     = align256(H_OFF + (size_t)N_NODES * D_HID * sizeof(float));
static constexpr size_t S2_OFF     = align256(S1_OFF + (size_t)N_NODES * D_HID * sizeof(float));
static constexpr size_t WS_TOTAL   = S2_OFF + (size_t)N_NODES * D_HID * sizeof(float);

// ---------------- preprocessing ----------------

__global__ void used_kernel(const int* __restrict__ seq, const int* __restrict__ res,
                            int* __restrict__ used) {
    int t = threadIdx.x;
    if (t < N_ADJ) used[t] = 0;
    __syncthreads();
    if (t == 0) {
        for (int i = 0; i < 3; ++i) used[seq[i]] = 1;
        for (int i = 0; i < 3; ++i) used[res[i]] = 1;
    }
}

__global__ __launch_bounds__(HIST_BLOCK) void hist_kernel(const int* __restrict__ rows,
                                                          const int* __restrict__ used,
                                                          int* __restrict__ cnt) {
    int a = blockIdx.x / BPA;
    if (!used[a]) return;
    int blk = blockIdx.x % BPA;
    int base = blk * (HIST_BLOCK * HIST_EPT) + threadIdx.x;
    const int* r = rows + (size_t)a * NNZ;
    int* c = cnt + (size_t)a * N_NODES;
#pragma unroll
    for (int i = 0; i < HIST_EPT; ++i) {
        int e = base + i * HIST_BLOCK;
        if (e < NNZ) atomicAdd(&c[r[e]], 1);
    }
}

__global__ __launch_bounds__(1024) void scan_kernel(const int* __restrict__ used,
                                                    int* __restrict__ cnt,      // in: counts, out: cursor (=excl prefix)
                                                    int* __restrict__ rowptr) { // out: excl prefix + total at [N]
    int a = blockIdx.x;
    if (!used[a]) return;
    int* c = cnt + (size_t)a * N_NODES;
    int* rp = rowptr + (size_t)a * (N_NODES + 1);
    const int SEG = (N_NODES + 1023) / 1024; // 49
    int tid = threadIdx.x;
    int base = tid * SEG;
    int sum = 0;
    for (int i = 0; i < SEG; ++i) {
        int idx = base + i;
        if (idx < N_NODES) sum += c[idx];
    }
    __shared__ int sm[1024];
    sm[tid] = sum;
    __syncthreads();
    for (int off = 1; off < 1024; off <<= 1) {
        int v = (tid >= off) ? sm[tid - off] : 0;
        __syncthreads();
        sm[tid] += v;
        __syncthreads();
    }
    int excl = sm[tid] - sum;
    if (tid == 1023) rp[N_NODES] = sm[1023];
    int run = excl;
    for (int i = 0; i < SEG; ++i) {
        int idx = base + i;
        if (idx < N_NODES) {
            int v = c[idx];
            rp[idx] = run;
            c[idx] = run; // cursor for scatter
            run += v;
        }
    }
}

__global__ __launch_bounds__(HIST_BLOCK) void scatter_kernel(const int* __restrict__ rows,
                                                             const int* __restrict__ cols,
                                                             const float* __restrict__ vals,
                                                             const int* __restrict__ used,
                                                             int* __restrict__ cursor,
                                                             int* __restrict__ scols,
                                                             float* __restrict__ svals) {
    int a = blockIdx.x / BPA;
    if (!used[a]) return;
    int blk = blockIdx.x % BPA;
    int base = blk * (HIST_BLOCK * HIST_EPT) + threadIdx.x;
    const int* r = rows + (size_t)a * NNZ;
    const int* cc = cols + (size_t)a * NNZ;
    const float* vv = vals + (size_t)a * NNZ;
    int* cur = cursor + (size_t)a * N_NODES;
    int* oc = scols + (size_t)a * NNZ;
    float* ov = svals + (size_t)a * NNZ;
#pragma unroll
    for (int i = 0; i < HIST_EPT; ++i) {
        int e = base + i * HIST_BLOCK;
        if (e < NNZ) {
            int row = r[e];
            int pos = atomicAdd(&cur[row], 1);
            oc[pos] = cc[e];
            ov[pos] = vv[e];
        }
    }
}

// ---------------- GEMM: h = x @ W + b ----------------
// 32 rows per 256-thread block; each wave computes 8 rows x 128 cols (float2/lane).

__global__ __launch_bounds__(256) void gemm_kernel(const float* __restrict__ x,
                                                   const float* __restrict__ W,
                                                   const float* __restrict__ b,
                                                   float* __restrict__ h) {
    __shared__ float xs[32][D_PREV]; // 32 KB
    int block_row0 = blockIdx.x * 32;
    int tid = threadIdx.x;
    const float4* x4 = (const float4*)x + (size_t)block_row0 * (D_PREV / 4);
    float4* xs4 = (float4*)xs;
    for (int i = tid; i < 32 * (D_PREV / 4); i += 256) {
        int row = block_row0 + (i >> 6); // 64 float4 per row
        xs4[i] = (row < N_NODES) ? x4[i] : float4{0.f, 0.f, 0.f, 0.f};
    }
    __syncthreads();

    int wave = tid >> 6, lane = tid & 63;
    int r0 = wave * 8;
    float2 bb = *(const float2*)&b[2 * lane];
    float2 acc[8];
#pragma unroll
    for (int r = 0; r < 8; ++r) acc[r] = bb;

    const float2* W2 = (const float2*)W; // row k: 64 float2
    for (int k = 0; k < D_PREV; k += 4) {
        float4 xr[8];
#pragma unroll
        for (int r = 0; r < 8; ++r) xr[r] = *(const float4*)&xs[r0 + r][k];
#pragma unroll
        for (int kk = 0; kk < 4; ++kk) {
            float2 w = W2[(size_t)(k + kk) * 64 + lane];
#pragma unroll
            for (int r = 0; r < 8; ++r) {
                float xv = ((const float*)&xr[r])[kk];
                acc[r].x = fmaf(xv, w.x, acc[r].x);
                acc[r].y = fmaf(xv, w.y, acc[r].y);
            }
        }
    }
#pragma unroll
    for (int r = 0; r < 8; ++r) {
        int row = block_row0 + r0 + r;
        if (row < N_NODES) *(float2*)&h[(size_t)row * D_HID + 2 * lane] = acc[r];
    }
}

// ---------------- SpMM (CSR gather, one wave per row) ----------------

__device__ __forceinline__ void spmm_row(const int* __restrict__ rowptr,
                                         const int* __restrict__ scols,
                                         const float* __restrict__ svals,
                                         int a, int row, int lane,
                                         const float* __restrict__ src, float2& acc) {
    const int* rp = rowptr + (size_t)a * (N_NODES + 1);
    int beg = rp[row], end = rp[row + 1];
    const int* sc = scols + (size_t)a * NNZ;
    const float* sv = svals + (size_t)a * NNZ;
    const float2* src2 = (const float2*)src;
    int e = beg;
    for (; e + 1 < end; e += 2) {
        int c0 = sc[e], c1 = sc[e + 1];
        float v0 = sv[e], v1 = sv[e + 1];
        float2 x0 = src2[(size_t)c0 * 64 + lane];
        float2 x1 = src2[(size_t)c1 * 64 + lane];
        acc.x = fmaf(v0, x0.x, acc.x);
        acc.y = fmaf(v0, x0.y, acc.y);
        acc.x = fmaf(v1, x1.x, acc.x);
        acc.y = fmaf(v1, x1.y, acc.y);
    }
    if (e < end) {
        int c0 = sc[e];
        float v0 = sv[e];
        float2 x0 = src2[(size_t)c0 * 64 + lane];
        acc.x = fmaf(v0, x0.x, acc.x);
        acc.y = fmaf(v0, x0.y, acc.y);
    }
}

__global__ __launch_bounds__(256) void spmm1_kernel(const int* __restrict__ rowptr,
                                                    const int* __restrict__ scols,
                                                    const float* __restrict__ svals,
                                                    const int* __restrict__ seq,
                                                    const float* __restrict__ h,
                                                    float* __restrict__ s1) {
    int row = blockIdx.x * 4 + (threadIdx.x >> 6);
    if (row >= N_NODES) return;
    int lane = threadIdx.x & 63;
    float2 acc = {0.f, 0.f};
    spmm_row(rowptr, scols, svals, seq[0], row, lane, h, acc);
    *(float2*)&s1[(size_t)row * D_HID + 2 * lane] = acc;
}

__global__ __launch_bounds__(256) void spmm2_kernel(const int* __restrict__ rowptr,
                                                    const int* __restrict__ scols,
                                                    const float* __restrict__ svals,
                                                    const int* __restrict__ seq,
                                                    const int* __restrict__ res,
                                                    const float* __restrict__ s1,
                                                    const float* __restrict__ h,
                                                    float* __restrict__ s2) {
    int row = blockIdx.x * 4 + (threadIdx.x >> 6);
    if (row >= N_NODES) return;
    int lane = threadIdx.x & 63;
    float2 acc = {0.f, 0.f};
    spmm_row(rowptr, scols, svals, seq[1], row, lane, s1, acc);
    spmm_row(rowptr, scols, svals, res[0], row, lane, h, acc);
    *(float2*)&s2[(size_t)row * D_HID + 2 * lane] = acc;
}

__global__ __launch_bounds__(256) void spmm3_ln_gelu_kernel(const int* __restrict__ rowptr,
                                                            const int* __restrict__ scols,
                                                            const float* __restrict__ svals,
                                                            const int* __restrict__ seq,
                                                            const int* __restrict__ res,
                                                            const float* __restrict__ s2,
                                                            const float* __restrict__ h,
                                                            const float* __restrict__ s1,
                                                            const float* __restrict__ gamma,
                                                            const float* __restrict__ beta,
                                                            float* __restrict__ out) {
    int row = blockIdx.x * 4 + (threadIdx.x >> 6);
    if (row >= N_NODES) return;
    int lane = threadIdx.x & 63;
    float2 acc = {0.f, 0.f};
    spmm_row(rowptr, scols, svals, seq[2], row, lane, s2, acc);
    spmm_row(rowptr, scols, svals, res[1], row, lane, h, acc);
    spmm_row(rowptr, scols, svals, res[2], row, lane, s1, acc);

    // LayerNorm over 128 dims held as float2 across the 64-lane wave
    float s = acc.x + acc.y;
    float sq = acc.x * acc.x + acc.y * acc.y;
#pragma unroll
    for (int m = 1; m < 64; m <<= 1) {
        s += __shfl_xor(s, m);
        sq += __shfl_xor(sq, m);
    }
    float mean = s * (1.0f / D_HID);
    float var = fmaxf(sq * (1.0f / D_HID) - mean * mean, 0.f);
    float inv = rsqrtf(var + LN_EPS);
    float2 g = *(const float2*)&gamma[2 * lane];
    float2 bt = *(const float2*)&beta[2 * lane];
    float n0 = (acc.x - mean) * inv * g.x + bt.x;
    float n1 = (acc.y - mean) * inv * g.y + bt.y;
    const float kInvSqrt2 = 0.70710678118654752f;
    float2 o;
    o.x = 0.5f * n0 * (1.f + erff(n0 * kInvSqrt2));
    o.y = 0.5f * n1 * (1.f + erff(n1 * kInvSqrt2));
    *(float2*)&out[(size_t)row * D_HID + 2 * lane] = o;
}

// ---------------- launch ----------------

extern "C" void kernel_launch(void* const* d_in, const int* in_sizes, int n_in,
                              void* d_out, int out_size, void* d_ws, size_t ws_size,
                              hipStream_t stream) {
    const float* x       = (const float*)d_in[0];
    const int*   adjRows = (const int*)d_in[1];
    const int*   adjCols = (const int*)d_in[2];
    const float* adjVals = (const float*)d_in[3];
    const int*   seq     = (const int*)d_in[4];
    const int*   res     = (const int*)d_in[5];
    const float* W       = (const float*)d_in[6];
    const float* b       = (const float*)d_in[7];
    const float* gamma   = (const float*)d_in[8];
    const float* beta    = (const float*)d_in[9];
    float* out = (float*)d_out;

    if (ws_size < WS_TOTAL) return; // workspace too small; fail loudly via validation

    char* ws = (char*)d_ws;
    int*   used   = (int*)(ws + USED_OFF);
    int*   rowptr = (int*)(ws + ROWPTR_OFF);
    int*   cursor = (int*)(ws + CURSOR_OFF);
    int*   scols  = (int*)(ws + SCOLS_OFF);
    float* svals  = (float*)(ws + SVALS_OFF);
    float* h      = (float*)(ws + H_OFF);
    float* s1     = (float*)(ws + S1_OFF);
    float* s2     = (float*)(ws + S2_OFF);

    // GEMM is independent of CSR preprocessing
    gemm_kernel<<<(N_NODES + 31) / 32, 256, 0, stream>>>(x, W, b, h);

    used_kernel<<<1, 64, 0, stream>>>(seq, res, used);
    hipMemsetAsync(cursor, 0, (size_t)N_ADJ * N_NODES * sizeof(int), stream);
    hist_kernel<<<N_ADJ * BPA, HIST_BLOCK, 0, stream>>>(adjRows, used, cursor);
    scan_kernel<<<N_ADJ, 1024, 0, stream>>>(used, cursor, rowptr);
    scatter_kernel<<<N_ADJ * BPA, HIST_BLOCK, 0, stream>>>(adjRows, adjCols, adjVals, used,
                                                           cursor, scols, svals);

    spmm1_kernel<<<(N_NODES + 3) / 4, 256, 0, stream>>>(rowptr, scols, svals, seq, h, s1);
    spmm2_kernel<<<(N_NODES + 3) / 4, 256, 0, stream>>>(rowptr, scols, svals, seq, res, s1, h, s2);
    spmm3_ln_gelu_kernel<<<(N_NODES + 3) / 4, 256, 0, stream>>>(rowptr, scols, svals, seq, res,
                                                                s2, h, s1, gamma, beta, out);
}

// Round 2
// 870.282 us; speedup vs baseline: 1.0809x; 1.0809x over previous
//
#include <hip/hip_runtime.h>

#define N_NODES 50000
#define N_ADJ 6
#define NNZ 800000
#define D_PREV 256
#define D_HID 128
#define LN_EPS 1e-5f

typedef unsigned int uint;
typedef unsigned short ushort;

static constexpr int HIST_EPT = 8;
static constexpr int HIST_BLOCK = 256;
static constexpr int BPA = (NNZ + HIST_BLOCK * HIST_EPT - 1) / (HIST_BLOCK * HIST_EPT); // 391

static constexpr size_t align256(size_t x) { return (x + 255) & ~(size_t)255; }
static constexpr size_t USED_OFF   = 0;
static constexpr size_t ROWPTR_OFF = align256(USED_OFF + N_ADJ * sizeof(int));
static constexpr size_t CURSOR_OFF = align256(ROWPTR_OFF + (size_t)N_ADJ * (N_NODES + 1) * sizeof(int));
static constexpr size_t EDGES_OFF  = align256(CURSOR_OFF + (size_t)N_ADJ * N_NODES * sizeof(int));
static constexpr size_t H_OFF      = align256(EDGES_OFF + (size_t)N_ADJ * NNZ * sizeof(int2));
static constexpr size_t S1_OFF     = align256(H_OFF + (size_t)N_NODES * D_HID * sizeof(ushort));
static constexpr size_t S2_OFF     = align256(S1_OFF + (size_t)N_NODES * D_HID * sizeof(ushort));
static constexpr size_t WS_TOTAL   = S2_OFF + (size_t)N_NODES * D_HID * sizeof(ushort);

__device__ __forceinline__ ushort f2bf(float f) {
    uint u = __float_as_uint(f);
    uint r = (u + 0x7FFFu + ((u >> 16) & 1u)) >> 16;
    return (ushort)r;
}

// ---------------- preprocessing ----------------

__global__ void used_kernel(const int* __restrict__ seq, const int* __restrict__ res,
                            int* __restrict__ used) {
    int t = threadIdx.x;
    if (t < N_ADJ) used[t] = 0;
    __syncthreads();
    if (t == 0) {
        for (int i = 0; i < 3; ++i) used[seq[i]] = 1;
        for (int i = 0; i < 3; ++i) used[res[i]] = 1;
    }
}

__global__ __launch_bounds__(HIST_BLOCK) void hist_kernel(const int* __restrict__ rows,
                                                          const int* __restrict__ used,
                                                          int* __restrict__ cnt) {
    int a = blockIdx.x / BPA;
    if (!used[a]) return;
    int blk = blockIdx.x % BPA;
    int base = blk * (HIST_BLOCK * HIST_EPT) + threadIdx.x;
    const int* r = rows + (size_t)a * NNZ;
    int* c = cnt + (size_t)a * N_NODES;
#pragma unroll
    for (int i = 0; i < HIST_EPT; ++i) {
        int e = base + i * HIST_BLOCK;
        if (e < NNZ) atomicAdd(&c[r[e]], 1);
    }
}

__global__ __launch_bounds__(1024) void scan_kernel(const int* __restrict__ used,
                                                    int* __restrict__ cnt,      // in: counts, out: cursor (=excl prefix)
                                                    int* __restrict__ rowptr) { // out: excl prefix + total at [N]
    int a = blockIdx.x;
    if (!used[a]) return;
    int* c = cnt + (size_t)a * N_NODES;
    int* rp = rowptr + (size_t)a * (N_NODES + 1);
    const int SEG = (N_NODES + 1023) / 1024; // 49
    int tid = threadIdx.x;
    int base = tid * SEG;
    int sum = 0;
    for (int i = 0; i < SEG; ++i) {
        int idx = base + i;
        if (idx < N_NODES) sum += c[idx];
    }
    __shared__ int sm[1024];
    sm[tid] = sum;
    __syncthreads();
    for (int off = 1; off < 1024; off <<= 1) {
        int v = (tid >= off) ? sm[tid - off] : 0;
        __syncthreads();
        sm[tid] += v;
        __syncthreads();
    }
    int excl = sm[tid] - sum;
    if (tid == 1023) rp[N_NODES] = sm[1023];
    int run = excl;
    for (int i = 0; i < SEG; ++i) {
        int idx = base + i;
        if (idx < N_NODES) {
            int v = c[idx];
            rp[idx] = run;
            c[idx] = run; // cursor for scatter
            run += v;
        }
    }
}

__global__ __launch_bounds__(HIST_BLOCK) void scatter_kernel(const int* __restrict__ rows,
                                                             const int* __restrict__ cols,
                                                             const float* __restrict__ vals,
                                                             const int* __restrict__ used,
                                                             int* __restrict__ cursor,
                                                             int2* __restrict__ edges) {
    int a = blockIdx.x / BPA;
    if (!used[a]) return;
    int blk = blockIdx.x % BPA;
    int base = blk * (HIST_BLOCK * HIST_EPT) + threadIdx.x;
    const int* r = rows + (size_t)a * NNZ;
    const int* cc = cols + (size_t)a * NNZ;
    const float* vv = vals + (size_t)a * NNZ;
    int* cur = cursor + (size_t)a * N_NODES;
    int2* oe = edges + (size_t)a * NNZ;
#pragma unroll
    for (int i = 0; i < HIST_EPT; ++i) {
        int e = base + i * HIST_BLOCK;
        if (e < NNZ) {
            int row = r[e];
            int pos = atomicAdd(&cur[row], 1);
            oe[pos] = int2{cc[e], __float_as_int(vv[e])};
        }
    }
}

// ---------------- GEMM: h = x @ W + b (bf16 output) ----------------

__global__ __launch_bounds__(256) void gemm_kernel(const float* __restrict__ x,
                                                   const float* __restrict__ W,
                                                   const float* __restrict__ b,
                                                   ushort* __restrict__ h) {
    __shared__ float xs[32][D_PREV]; // 32 KB
    int block_row0 = blockIdx.x * 32;
    int tid = threadIdx.x;
    const float4* x4 = (const float4*)x + (size_t)block_row0 * (D_PREV / 4);
    float4* xs4 = (float4*)xs;
    for (int i = tid; i < 32 * (D_PREV / 4); i += 256) {
        int row = block_row0 + (i >> 6); // 64 float4 per row
        xs4[i] = (row < N_NODES) ? x4[i] : float4{0.f, 0.f, 0.f, 0.f};
    }
    __syncthreads();

    int wave = tid >> 6, lane = tid & 63;
    int r0 = wave * 8;
    float2 bb = *(const float2*)&b[2 * lane];
    float2 acc[8];
#pragma unroll
    for (int r = 0; r < 8; ++r) acc[r] = bb;

    const float2* W2 = (const float2*)W; // row k: 64 float2
    for (int k = 0; k < D_PREV; k += 4) {
        float4 xr[8];
#pragma unroll
        for (int r = 0; r < 8; ++r) xr[r] = *(const float4*)&xs[r0 + r][k];
#pragma unroll
        for (int kk = 0; kk < 4; ++kk) {
            float2 w = W2[(size_t)(k + kk) * 64 + lane];
#pragma unroll
            for (int r = 0; r < 8; ++r) {
                float xv = ((const float*)&xr[r])[kk];
                acc[r].x = fmaf(xv, w.x, acc[r].x);
                acc[r].y = fmaf(xv, w.y, acc[r].y);
            }
        }
    }
#pragma unroll
    for (int r = 0; r < 8; ++r) {
        int row = block_row0 + r0 + r;
        if (row < N_NODES) {
            ushort2 o = {f2bf(acc[r].x), f2bf(acc[r].y)};
            *(ushort2*)&h[(size_t)row * D_HID + 2 * lane] = o;
        }
    }
}

// ---------------- SpMM (CSR gather, one wave per row, bf16 sources) ----------------

__device__ __forceinline__ void spmm_row(const int* __restrict__ rowptr,
                                         const int2* __restrict__ edges,
                                         int a, int row, int lane,
                                         const uint* __restrict__ src, float2& acc) {
    const int* rp = rowptr + (size_t)a * (N_NODES + 1);
    int beg = rp[row], end = rp[row + 1];
    const int2* ed = edges + (size_t)a * NNZ;
    int e = beg;
    for (; e + 1 < end; e += 2) {
        int2 e0 = ed[e], e1 = ed[e + 1];
        uint u0 = src[(size_t)e0.x * 64 + lane];
        uint u1 = src[(size_t)e1.x * 64 + lane];
        float v0 = __int_as_float(e0.y), v1 = __int_as_float(e1.y);
        acc.x = fmaf(v0, __uint_as_float(u0 << 16), acc.x);
        acc.y = fmaf(v0, __uint_as_float(u0 & 0xFFFF0000u), acc.y);
        acc.x = fmaf(v1, __uint_as_float(u1 << 16), acc.x);
        acc.y = fmaf(v1, __uint_as_float(u1 & 0xFFFF0000u), acc.y);
    }
    if (e < end) {
        int2 e0 = ed[e];
        uint u0 = src[(size_t)e0.x * 64 + lane];
        float v0 = __int_as_float(e0.y);
        acc.x = fmaf(v0, __uint_as_float(u0 << 16), acc.x);
        acc.y = fmaf(v0, __uint_as_float(u0 & 0xFFFF0000u), acc.y);
    }
}

__global__ __launch_bounds__(256) void spmm1_kernel(const int* __restrict__ rowptr,
                                                    const int2* __restrict__ edges,
                                                    const int* __restrict__ seq,
                                                    const uint* __restrict__ h,
                                                    ushort* __restrict__ s1) {
    int row = blockIdx.x * 4 + (threadIdx.x >> 6);
    if (row >= N_NODES) return;
    int lane = threadIdx.x & 63;
    float2 acc = {0.f, 0.f};
    spmm_row(rowptr, edges, seq[0], row, lane, h, acc);
    ushort2 o = {f2bf(acc.x), f2bf(acc.y)};
    *(ushort2*)&s1[(size_t)row * D_HID + 2 * lane] = o;
}

__global__ __launch_bounds__(256) void spmm2_kernel(const int* __restrict__ rowptr,
                                                    const int2* __restrict__ edges,
                                                    const int* __restrict__ seq,
                                                    const int* __restrict__ res,
                                                    const uint* __restrict__ s1,
                                                    const uint* __restrict__ h,
                                                    ushort* __restrict__ s2) {
    int row = blockIdx.x * 4 + (threadIdx.x >> 6);
    if (row >= N_NODES) return;
    int lane = threadIdx.x & 63;
    float2 acc = {0.f, 0.f};
    spmm_row(rowptr, edges, seq[1], row, lane, s1, acc);
    spmm_row(rowptr, edges, res[0], row, lane, h, acc);
    ushort2 o = {f2bf(acc.x), f2bf(acc.y)};
    *(ushort2*)&s2[(size_t)row * D_HID + 2 * lane] = o;
}

__global__ __launch_bounds__(256) void spmm3_ln_gelu_kernel(const int* __restrict__ rowptr,
                                                            const int2* __restrict__ edges,
                                                            const int* __restrict__ seq,
                                                            const int* __restrict__ res,
                                                            const uint* __restrict__ s2,
                                                            const uint* __restrict__ h,
                                                            const uint* __restrict__ s1,
                                                            const float* __restrict__ gamma,
                                                            const float* __restrict__ beta,
                                                            float* __restrict__ out) {
    int row = blockIdx.x * 4 + (threadIdx.x >> 6);
    if (row >= N_NODES) return;
    int lane = threadIdx.x & 63;
    float2 acc = {0.f, 0.f};
    spmm_row(rowptr, edges, seq[2], row, lane, s2, acc);
    spmm_row(rowptr, edges, res[1], row, lane, h, acc);
    spmm_row(rowptr, edges, res[2], row, lane, s1, acc);

    // LayerNorm over 128 dims held as float2 across the 64-lane wave
    float s = acc.x + acc.y;
    float sq = acc.x * acc.x + acc.y * acc.y;
#pragma unroll
    for (int m = 1; m < 64; m <<= 1) {
        s += __shfl_xor(s, m);
        sq += __shfl_xor(sq, m);
    }
    float mean = s * (1.0f / D_HID);
    float var = fmaxf(sq * (1.0f / D_HID) - mean * mean, 0.f);
    float inv = rsqrtf(var + LN_EPS);
    float2 g = *(const float2*)&gamma[2 * lane];
    float2 bt = *(const float2*)&beta[2 * lane];
    float n0 = (acc.x - mean) * inv * g.x + bt.x;
    float n1 = (acc.y - mean) * inv * g.y + bt.y;
    const float kInvSqrt2 = 0.70710678118654752f;
    float2 o;
    o.x = 0.5f * n0 * (1.f + erff(n0 * kInvSqrt2));
    o.y = 0.5f * n1 * (1.f + erff(n1 * kInvSqrt2));
    *(float2*)&out[(size_t)row * D_HID + 2 * lane] = o;
}

// ---------------- launch ----------------

extern "C" void kernel_launch(void* const* d_in, const int* in_sizes, int n_in,
                              void* d_out, int out_size, void* d_ws, size_t ws_size,
                              hipStream_t stream) {
    const float* x       = (const float*)d_in[0];
    const int*   adjRows = (const int*)d_in[1];
    const int*   adjCols = (const int*)d_in[2];
    const float* adjVals = (const float*)d_in[3];
    const int*   seq     = (const int*)d_in[4];
    const int*   res     = (const int*)d_in[5];
    const float* W       = (const float*)d_in[6];
    const float* b       = (const float*)d_in[7];
    const float* gamma   = (const float*)d_in[8];
    const float* beta    = (const float*)d_in[9];
    float* out = (float*)d_out;

    if (ws_size < WS_TOTAL) return;

    char* ws = (char*)d_ws;
    int*    used   = (int*)(ws + USED_OFF);
    int*    rowptr = (int*)(ws + ROWPTR_OFF);
    int*    cursor = (int*)(ws + CURSOR_OFF);
    int2*   edges  = (int2*)(ws + EDGES_OFF);
    ushort* h      = (ushort*)(ws + H_OFF);
    ushort* s1     = (ushort*)(ws + S1_OFF);
    ushort* s2     = (ushort*)(ws + S2_OFF);

    gemm_kernel<<<(N_NODES + 31) / 32, 256, 0, stream>>>(x, W, b, h);

    used_kernel<<<1, 64, 0, stream>>>(seq, res, used);
    hipMemsetAsync(cursor, 0, (size_t)N_ADJ * N_NODES * sizeof(int), stream);
    hist_kernel<<<N_ADJ * BPA, HIST_BLOCK, 0, stream>>>(adjRows, used, cursor);
    scan_kernel<<<N_ADJ, 1024, 0, stream>>>(used, cursor, rowptr);
    scatter_kernel<<<N_ADJ * BPA, HIST_BLOCK, 0, stream>>>(adjRows, adjCols, adjVals, used,
                                                           cursor, edges);

    spmm1_kernel<<<(N_NODES + 3) / 4, 256, 0, stream>>>(rowptr, edges, seq, (const uint*)h, s1);
    spmm2_kernel<<<(N_NODES + 3) / 4, 256, 0, stream>>>(rowptr, edges, seq, res,
                                                        (const uint*)s1, (const uint*)h, s2);
    spmm3_ln_gelu_kernel<<<(N_NODES + 3) / 4, 256, 0, stream>>>(rowptr, edges, seq, res,
                                                                (const uint*)s2, (const uint*)h,
                                                                (const uint*)s1, gamma, beta, out);
}

// Round 3
// 441.864 us; speedup vs baseline: 2.1290x; 1.9696x over previous
//
#include <hip/hip_runtime.h>

#define N_NODES 50000
#define N_ADJ 6
#define NNZ 800000
#define D_PREV 256
#define D_HID 128
#define LN_EPS 1e-5f

typedef unsigned int uint;
typedef unsigned short ushort;

static constexpr int EPT = 8;
static constexpr int BLK = 256;
static constexpr int BPA = (NNZ + BLK * EPT - 1) / (BLK * EPT); // 391

static constexpr int BKT_SHIFT = 9;
static constexpr int BKT_ROWS = 1 << BKT_SHIFT;                       // 512
static constexpr int NBKT = (N_NODES + BKT_ROWS - 1) / BKT_ROWS;      // 98

static constexpr size_t align256(size_t x) { return (x + 255) & ~(size_t)255; }
static constexpr size_t USED_OFF   = 0;
static constexpr size_t BCNT_OFF   = align256(USED_OFF + N_ADJ * sizeof(int));
static constexpr size_t GCUR_OFF   = BCNT_OFF + (size_t)N_ADJ * NBKT * sizeof(int); // adjacent -> one memset
static constexpr size_t BBASE_OFF  = align256(GCUR_OFF + (size_t)N_ADJ * NBKT * sizeof(int));
static constexpr size_t ROWPTR_OFF = align256(BBASE_OFF + (size_t)N_ADJ * (NBKT + 1) * sizeof(int));
static constexpr size_t BUCK_OFF   = align256(ROWPTR_OFF + (size_t)N_ADJ * (N_NODES + 1) * sizeof(int));
static constexpr size_t SORT_OFF   = align256(BUCK_OFF + (size_t)N_ADJ * NNZ * sizeof(int2));
static constexpr size_t H_OFF      = align256(SORT_OFF + (size_t)N_ADJ * NNZ * sizeof(int2));
static constexpr size_t S1_OFF     = align256(H_OFF + (size_t)N_NODES * D_HID * sizeof(ushort));
static constexpr size_t S2_OFF     = align256(S1_OFF + (size_t)N_NODES * D_HID * sizeof(ushort));
static constexpr size_t WS_TOTAL   = S2_OFF + (size_t)N_NODES * D_HID * sizeof(ushort);

__device__ __forceinline__ ushort f2bf(float f) {
    uint u = __float_as_uint(f);
    uint r = (u + 0x7FFFu + ((u >> 16) & 1u)) >> 16;
    return (ushort)r;
}

// ---------------- preprocessing ----------------

__global__ void used_kernel(const int* __restrict__ seq, const int* __restrict__ res,
                            int* __restrict__ used) {
    int t = threadIdx.x;
    if (t < N_ADJ) used[t] = 0;
    __syncthreads();
    if (t == 0) {
        for (int i = 0; i < 3; ++i) used[seq[i]] = 1;
        for (int i = 0; i < 3; ++i) used[res[i]] = 1;
    }
}

// Level 1a: coarse bucket histogram (LDS-aggregated)
__global__ __launch_bounds__(BLK) void bhist_kernel(const int* __restrict__ rows,
                                                    const int* __restrict__ used,
                                                    int* __restrict__ bcnt) {
    int a = blockIdx.x / BPA;
    if (!used[a]) return;
    __shared__ int lcnt[NBKT];
    int t = threadIdx.x;
    if (t < NBKT) lcnt[t] = 0;
    __syncthreads();
    int blk = blockIdx.x % BPA;
    int base = blk * (BLK * EPT) + t;
    const int* r = rows + (size_t)a * NNZ;
#pragma unroll
    for (int i = 0; i < EPT; ++i) {
        int e = base + i * BLK;
        if (e < NNZ) atomicAdd(&lcnt[r[e] >> BKT_SHIFT], 1);
    }
    __syncthreads();
    if (t < NBKT) atomicAdd(&bcnt[a * NBKT + t], lcnt[t]);
}

// Level 1b: tiny scan of 98 bucket counts per adjacency
__global__ void bscan_kernel(const int* __restrict__ used,
                             const int* __restrict__ bcnt,
                             int* __restrict__ bbase,
                             int* __restrict__ rowptr) {
    int a = blockIdx.x;
    if (!used[a]) return;
    if (threadIdx.x == 0) {
        int run = 0;
        for (int k = 0; k < NBKT; ++k) {
            bbase[a * (NBKT + 1) + k] = run;
            run += bcnt[a * NBKT + k];
        }
        bbase[a * (NBKT + 1) + NBKT] = run;           // == NNZ
        rowptr[(size_t)a * (N_NODES + 1) + N_NODES] = run;
    }
}

// Level 1c: scatter edges into coarse buckets (exact regions, per-block runs)
__global__ __launch_bounds__(BLK) void bscatter_kernel(const int* __restrict__ rows,
                                                       const int* __restrict__ cols,
                                                       const float* __restrict__ vals,
                                                       const int* __restrict__ used,
                                                       const int* __restrict__ bbase,
                                                       int* __restrict__ gcur,
                                                       int2* __restrict__ bucketed) {
    int a = blockIdx.x / BPA;
    if (!used[a]) return;
    __shared__ int lcnt[NBKT];
    __shared__ int lbase[NBKT];
    int t = threadIdx.x;
    if (t < NBKT) lcnt[t] = 0;
    __syncthreads();
    int blk = blockIdx.x % BPA;
    int base = blk * (BLK * EPT) + t;
    const int* rr = rows + (size_t)a * NNZ;
    const int* cc = cols + (size_t)a * NNZ;
    const float* vv = vals + (size_t)a * NNZ;
    int ebk[EPT], ernk[EPT], ecol[EPT];
    float eval[EPT];
#pragma unroll
    for (int i = 0; i < EPT; ++i) {
        int e = base + i * BLK;
        ebk[i] = -1;
        if (e < NNZ) {
            int row = rr[e];
            ecol[i] = cc[e];
            eval[i] = vv[e];
            int bk = row >> BKT_SHIFT;
            ebk[i] = (bk << 16) | (row & (BKT_ROWS - 1));
            ernk[i] = atomicAdd(&lcnt[bk], 1);
        }
    }
    __syncthreads();
    if (t < NBKT) lbase[t] = atomicAdd(&gcur[a * NBKT + t], lcnt[t]);
    __syncthreads();
    int2* ob = bucketed + (size_t)a * NNZ;
#pragma unroll
    for (int i = 0; i < EPT; ++i) {
        if (ebk[i] >= 0) {
            int bk = ebk[i] >> 16;
            int rl = ebk[i] & 0xFFFF;
            int pos = bbase[a * (NBKT + 1) + bk] + lbase[bk] + ernk[i];
            ob[pos] = int2{(rl << 16) | ecol[i], __float_as_int(eval[i])};
        }
    }
}

// Level 2: per-bucket fine counting sort (LDS hist/cursors; writes stay in a ~65KB L2-hot region)
__global__ __launch_bounds__(512) void bsort_kernel(const int* __restrict__ used,
                                                    const int* __restrict__ bbase,
                                                    const int2* __restrict__ bucketed,
                                                    int2* __restrict__ sorted,
                                                    int* __restrict__ rowptr) {
    int a = blockIdx.x / NBKT;
    if (!used[a]) return;
    int b = blockIdx.x % NBKT;
    int base = bbase[a * (NBKT + 1) + b];
    int cnt  = bbase[a * (NBKT + 1) + b + 1] - base;
    int t = threadIdx.x;

    __shared__ int sm[BKT_ROWS];   // hist -> inclusive scan
    __shared__ int cur[BKT_ROWS];  // cursors
    sm[t] = 0;
    __syncthreads();

    const int2* in = bucketed + (size_t)a * NNZ + base;
    for (int i = t; i < cnt; i += 512) {
        atomicAdd(&sm[in[i].x >> 16], 1);
    }
    __syncthreads();
    int own = sm[t];
    for (int off = 1; off < BKT_ROWS; off <<= 1) {
        int v = (t >= off) ? sm[t - off] : 0;
        __syncthreads();
        sm[t] += v;
        __syncthreads();
    }
    int excl = sm[t] - own;
    int row = b * BKT_ROWS + t;
    if (row < N_NODES) rowptr[(size_t)a * (N_NODES + 1) + row] = base + excl;
    cur[t] = excl;
    __syncthreads();

    int2* outp = sorted + (size_t)a * NNZ + base;
    for (int i = t; i < cnt; i += 512) {
        int2 e = in[i];
        int r = e.x >> 16;
        int pos = atomicAdd(&cur[r], 1);
        outp[pos] = int2{e.x & 0xFFFF, e.y};
    }
}

// ---------------- GEMM: h = x @ W + b (bf16 output) ----------------

__global__ __launch_bounds__(256) void gemm_kernel(const float* __restrict__ x,
                                                   const float* __restrict__ W,
                                                   const float* __restrict__ b,
                                                   ushort* __restrict__ h) {
    __shared__ float xs[32][D_PREV]; // 32 KB
    int block_row0 = blockIdx.x * 32;
    int tid = threadIdx.x;
    const float4* x4 = (const float4*)x + (size_t)block_row0 * (D_PREV / 4);
    float4* xs4 = (float4*)xs;
    for (int i = tid; i < 32 * (D_PREV / 4); i += 256) {
        int row = block_row0 + (i >> 6);
        xs4[i] = (row < N_NODES) ? x4[i] : float4{0.f, 0.f, 0.f, 0.f};
    }
    __syncthreads();

    int wave = tid >> 6, lane = tid & 63;
    int r0 = wave * 8;
    float2 bb = *(const float2*)&b[2 * lane];
    float2 acc[8];
#pragma unroll
    for (int r = 0; r < 8; ++r) acc[r] = bb;

    const float2* W2 = (const float2*)W;
    for (int k = 0; k < D_PREV; k += 4) {
        float4 xr[8];
#pragma unroll
        for (int r = 0; r < 8; ++r) xr[r] = *(const float4*)&xs[r0 + r][k];
#pragma unroll
        for (int kk = 0; kk < 4; ++kk) {
            float2 w = W2[(size_t)(k + kk) * 64 + lane];
#pragma unroll
            for (int r = 0; r < 8; ++r) {
                float xv = ((const float*)&xr[r])[kk];
                acc[r].x = fmaf(xv, w.x, acc[r].x);
                acc[r].y = fmaf(xv, w.y, acc[r].y);
            }
        }
    }
#pragma unroll
    for (int r = 0; r < 8; ++r) {
        int row = block_row0 + r0 + r;
        if (row < N_NODES) {
            ushort2 o = {f2bf(acc[r].x), f2bf(acc[r].y)};
            *(ushort2*)&h[(size_t)row * D_HID + 2 * lane] = o;
        }
    }
}

// ---------------- SpMM (CSR gather, one wave per row, bf16 sources) ----------------

__device__ __forceinline__ void spmm_row(const int* __restrict__ rowptr,
                                         const int2* __restrict__ edges,
                                         int a, int row, int lane,
                                         const uint* __restrict__ src, float2& acc) {
    const int* rp = rowptr + (size_t)a * (N_NODES + 1);
    int beg = rp[row], end = rp[row + 1];
    const int2* ed = edges + (size_t)a * NNZ;
    int e = beg;
    for (; e + 1 < end; e += 2) {
        int2 e0 = ed[e], e1 = ed[e + 1];
        uint u0 = src[(size_t)e0.x * 64 + lane];
        uint u1 = src[(size_t)e1.x * 64 + lane];
        float v0 = __int_as_float(e0.y), v1 = __int_as_float(e1.y);
        acc.x = fmaf(v0, __uint_as_float(u0 << 16), acc.x);
        acc.y = fmaf(v0, __uint_as_float(u0 & 0xFFFF0000u), acc.y);
        acc.x = fmaf(v1, __uint_as_float(u1 << 16), acc.x);
        acc.y = fmaf(v1, __uint_as_float(u1 & 0xFFFF0000u), acc.y);
    }
    if (e < end) {
        int2 e0 = ed[e];
        uint u0 = src[(size_t)e0.x * 64 + lane];
        float v0 = __int_as_float(e0.y);
        acc.x = fmaf(v0, __uint_as_float(u0 << 16), acc.x);
        acc.y = fmaf(v0, __uint_as_float(u0 & 0xFFFF0000u), acc.y);
    }
}

__global__ __launch_bounds__(256) void spmm1_kernel(const int* __restrict__ rowptr,
                                                    const int2* __restrict__ edges,
                                                    const int* __restrict__ seq,
                                                    const uint* __restrict__ h,
                                                    ushort* __restrict__ s1) {
    int row = blockIdx.x * 4 + (threadIdx.x >> 6);
    if (row >= N_NODES) return;
    int lane = threadIdx.x & 63;
    float2 acc = {0.f, 0.f};
    spmm_row(rowptr, edges, seq[0], row, lane, h, acc);
    ushort2 o = {f2bf(acc.x), f2bf(acc.y)};
    *(ushort2*)&s1[(size_t)row * D_HID + 2 * lane] = o;
}

__global__ __launch_bounds__(256) void spmm2_kernel(const int* __restrict__ rowptr,
                                                    const int2* __restrict__ edges,
                                                    const int* __restrict__ seq,
                                                    const int* __restrict__ res,
                                                    const uint* __restrict__ s1,
                                                    const uint* __restrict__ h,
                                                    ushort* __restrict__ s2) {
    int row = blockIdx.x * 4 + (threadIdx.x >> 6);
    if (row >= N_NODES) return;
    int lane = threadIdx.x & 63;
    float2 acc = {0.f, 0.f};
    spmm_row(rowptr, edges, seq[1], row, lane, s1, acc);
    spmm_row(rowptr, edges, res[0], row, lane, h, acc);
    ushort2 o = {f2bf(acc.x), f2bf(acc.y)};
    *(ushort2*)&s2[(size_t)row * D_HID + 2 * lane] = o;
}

__global__ __launch_bounds__(256) void spmm3_ln_gelu_kernel(const int* __restrict__ rowptr,
                                                            const int2* __restrict__ edges,
                                                            const int* __restrict__ seq,
                                                            const int* __restrict__ res,
                                                            const uint* __restrict__ s2,
                                                            const uint* __restrict__ h,
                                                            const uint* __restrict__ s1,
                                                            const float* __restrict__ gamma,
                                                            const float* __restrict__ beta,
                                                            float* __restrict__ out) {
    int row = blockIdx.x * 4 + (threadIdx.x >> 6);
    if (row >= N_NODES) return;
    int lane = threadIdx.x & 63;
    float2 acc = {0.f, 0.f};
    spmm_row(rowptr, edges, seq[2], row, lane, s2, acc);
    spmm_row(rowptr, edges, res[1], row, lane, h, acc);
    spmm_row(rowptr, edges, res[2], row, lane, s1, acc);

    float s = acc.x + acc.y;
    float sq = acc.x * acc.x + acc.y * acc.y;
#pragma unroll
    for (int m = 1; m < 64; m <<= 1) {
        s += __shfl_xor(s, m);
        sq += __shfl_xor(sq, m);
    }
    float mean = s * (1.0f / D_HID);
    float var = fmaxf(sq * (1.0f / D_HID) - mean * mean, 0.f);
    float inv = rsqrtf(var + LN_EPS);
    float2 g = *(const float2*)&gamma[2 * lane];
    float2 bt = *(const float2*)&beta[2 * lane];
    float n0 = (acc.x - mean) * inv * g.x + bt.x;
    float n1 = (acc.y - mean) * inv * g.y + bt.y;
    const float kInvSqrt2 = 0.70710678118654752f;
    float2 o;
    o.x = 0.5f * n0 * (1.f + erff(n0 * kInvSqrt2));
    o.y = 0.5f * n1 * (1.f + erff(n1 * kInvSqrt2));
    *(float2*)&out[(size_t)row * D_HID + 2 * lane] = o;
}

// ---------------- launch ----------------

extern "C" void kernel_launch(void* const* d_in, const int* in_sizes, int n_in,
                              void* d_out, int out_size, void* d_ws, size_t ws_size,
                              hipStream_t stream) {
    const float* x       = (const float*)d_in[0];
    const int*   adjRows = (const int*)d_in[1];
    const int*   adjCols = (const int*)d_in[2];
    const float* adjVals = (const float*)d_in[3];
    const int*   seq     = (const int*)d_in[4];
    const int*   res     = (const int*)d_in[5];
    const float* W       = (const float*)d_in[6];
    const float* b       = (const float*)d_in[7];
    const float* gamma   = (const float*)d_in[8];
    const float* beta    = (const float*)d_in[9];
    float* out = (float*)d_out;

    if (ws_size < WS_TOTAL) return;

    char* ws = (char*)d_ws;
    int*    used     = (int*)(ws + USED_OFF);
    int*    bcnt     = (int*)(ws + BCNT_OFF);
    int*    gcur     = (int*)(ws + GCUR_OFF);
    int*    bbase    = (int*)(ws + BBASE_OFF);
    int*    rowptr   = (int*)(ws + ROWPTR_OFF);
    int2*   bucketed = (int2*)(ws + BUCK_OFF);
    int2*   sorted   = (int2*)(ws + SORT_OFF);
    ushort* h        = (ushort*)(ws + H_OFF);
    ushort* s1       = (ushort*)(ws + S1_OFF);
    ushort* s2       = (ushort*)(ws + S2_OFF);

    gemm_kernel<<<(N_NODES + 31) / 32, 256, 0, stream>>>(x, W, b, h);

    used_kernel<<<1, 64, 0, stream>>>(seq, res, used);
    hipMemsetAsync(bcnt, 0, (size_t)2 * N_ADJ * NBKT * sizeof(int), stream); // bcnt + gcur
    bhist_kernel<<<N_ADJ * BPA, BLK, 0, stream>>>(adjRows, used, bcnt);
    bscan_kernel<<<N_ADJ, 64, 0, stream>>>(used, bcnt, bbase, rowptr);
    bscatter_kernel<<<N_ADJ * BPA, BLK, 0, stream>>>(adjRows, adjCols, adjVals, used,
                                                     bbase, gcur, bucketed);
    bsort_kernel<<<N_ADJ * NBKT, 512, 0, stream>>>(used, bbase, bucketed, sorted, rowptr);

    spmm1_kernel<<<(N_NODES + 3) / 4, 256, 0, stream>>>(rowptr, sorted, seq, (const uint*)h, s1);
    spmm2_kernel<<<(N_NODES + 3) / 4, 256, 0, stream>>>(rowptr, sorted, seq, res,
                                                        (const uint*)s1, (const uint*)h, s2);
    spmm3_ln_gelu_kernel<<<(N_NODES + 3) / 4, 256, 0, stream>>>(rowptr, sorted, seq, res,
                                                                (const uint*)s2, (const uint*)h,
                                                                (const uint*)s1, gamma, beta, out);
}

// Round 4
// 329.400 us; speedup vs baseline: 2.8558x; 1.3414x over previous
//
#include <hip/hip_runtime.h>

#define N_NODES 50000
#define N_ADJ 6
#define NNZ 800000
#define D_PREV 256
#define D_HID 128
#define LN_EPS 1e-5f

typedef unsigned int uint;
typedef unsigned short ushort;

static constexpr int EPT = 8;
static constexpr int BLK = 256;
static constexpr int BPA = (NNZ + BLK * EPT - 1) / (BLK * EPT); // 391

static constexpr int BKT_SHIFT = 9;
static constexpr int BKT_ROWS = 1 << BKT_SHIFT;                       // 512
static constexpr int NBKT = (N_NODES + BKT_ROWS - 1) / BKT_ROWS;      // 98

static constexpr size_t align256(size_t x) { return (x + 255) & ~(size_t)255; }
static constexpr size_t USED_OFF   = 0;
static constexpr size_t BCNT_OFF   = align256(USED_OFF + N_ADJ * sizeof(int));
static constexpr size_t GCUR_OFF   = BCNT_OFF + (size_t)N_ADJ * NBKT * sizeof(int); // adjacent -> one memset
static constexpr size_t BBASE_OFF  = align256(GCUR_OFF + (size_t)N_ADJ * NBKT * sizeof(int));
static constexpr size_t ROWPTR_OFF = align256(BBASE_OFF + (size_t)N_ADJ * (NBKT + 1) * sizeof(int));
static constexpr size_t BUCK_OFF   = align256(ROWPTR_OFF + (size_t)N_ADJ * (N_NODES + 1) * sizeof(int));
static constexpr size_t SORT_OFF   = align256(BUCK_OFF + (size_t)N_ADJ * NNZ * sizeof(int2));
static constexpr size_t H_OFF      = align256(SORT_OFF + (size_t)N_ADJ * NNZ * sizeof(int2));
static constexpr size_t S1_OFF     = align256(H_OFF + (size_t)N_NODES * D_HID * sizeof(ushort));
static constexpr size_t S2_OFF     = align256(S1_OFF + (size_t)N_NODES * D_HID * sizeof(ushort));
static constexpr size_t WS_TOTAL   = S2_OFF + (size_t)N_NODES * D_HID * sizeof(ushort);

__device__ __forceinline__ ushort f2bf(float f) {
    uint u = __float_as_uint(f);
    uint r = (u + 0x7FFFu + ((u >> 16) & 1u)) >> 16;
    return (ushort)r;
}

// ---------------- preprocessing ----------------

__global__ void used_kernel(const int* __restrict__ seq, const int* __restrict__ res,
                            int* __restrict__ used) {
    int t = threadIdx.x;
    if (t < N_ADJ) used[t] = 0;
    __syncthreads();
    if (t == 0) {
        for (int i = 0; i < 3; ++i) used[seq[i]] = 1;
        for (int i = 0; i < 3; ++i) used[res[i]] = 1;
    }
}

// Level 1a: coarse bucket histogram (LDS-aggregated)
__global__ __launch_bounds__(BLK) void bhist_kernel(const int* __restrict__ rows,
                                                    const int* __restrict__ used,
                                                    int* __restrict__ bcnt) {
    int a = blockIdx.x / BPA;
    if (!used[a]) return;
    __shared__ int lcnt[NBKT];
    int t = threadIdx.x;
    if (t < NBKT) lcnt[t] = 0;
    __syncthreads();
    int blk = blockIdx.x % BPA;
    int base = blk * (BLK * EPT) + t;
    const int* r = rows + (size_t)a * NNZ;
#pragma unroll
    for (int i = 0; i < EPT; ++i) {
        int e = base + i * BLK;
        if (e < NNZ) atomicAdd(&lcnt[r[e] >> BKT_SHIFT], 1);
    }
    __syncthreads();
    if (t < NBKT) atomicAdd(&bcnt[a * NBKT + t], lcnt[t]);
}

// Level 1b: tiny scan of 98 bucket counts per adjacency
__global__ void bscan_kernel(const int* __restrict__ used,
                             const int* __restrict__ bcnt,
                             int* __restrict__ bbase,
                             int* __restrict__ rowptr) {
    int a = blockIdx.x;
    if (!used[a]) return;
    if (threadIdx.x == 0) {
        int run = 0;
        for (int k = 0; k < NBKT; ++k) {
            bbase[a * (NBKT + 1) + k] = run;
            run += bcnt[a * NBKT + k];
        }
        bbase[a * (NBKT + 1) + NBKT] = run;           // == NNZ
        rowptr[(size_t)a * (N_NODES + 1) + N_NODES] = run;
    }
}

// Level 1c: scatter edges into coarse buckets (exact regions, per-block runs)
__global__ __launch_bounds__(BLK) void bscatter_kernel(const int* __restrict__ rows,
                                                       const int* __restrict__ cols,
                                                       const float* __restrict__ vals,
                                                       const int* __restrict__ used,
                                                       const int* __restrict__ bbase,
                                                       int* __restrict__ gcur,
                                                       int2* __restrict__ bucketed) {
    int a = blockIdx.x / BPA;
    if (!used[a]) return;
    __shared__ int lcnt[NBKT];
    __shared__ int lbase[NBKT];
    __shared__ int sbase[NBKT];
    int t = threadIdx.x;
    if (t < NBKT) {
        lcnt[t] = 0;
        sbase[t] = bbase[a * (NBKT + 1) + t];
    }
    __syncthreads();
    int blk = blockIdx.x % BPA;
    int base = blk * (BLK * EPT) + t;
    const int* rr = rows + (size_t)a * NNZ;
    const int* cc = cols + (size_t)a * NNZ;
    const float* vv = vals + (size_t)a * NNZ;
    int ebk[EPT], ernk[EPT], ecol[EPT];
    float eval[EPT];
#pragma unroll
    for (int i = 0; i < EPT; ++i) {
        int e = base + i * BLK;
        ebk[i] = -1;
        if (e < NNZ) {
            int row = rr[e];
            ecol[i] = cc[e];
            eval[i] = vv[e];
            int bk = row >> BKT_SHIFT;
            ebk[i] = (bk << 16) | (row & (BKT_ROWS - 1));
            ernk[i] = atomicAdd(&lcnt[bk], 1);
        }
    }
    __syncthreads();
    if (t < NBKT) lbase[t] = atomicAdd(&gcur[a * NBKT + t], lcnt[t]);
    __syncthreads();
    int2* ob = bucketed + (size_t)a * NNZ;
#pragma unroll
    for (int i = 0; i < EPT; ++i) {
        if (ebk[i] >= 0) {
            int bk = ebk[i] >> 16;
            int rl = ebk[i] & 0xFFFF;
            int pos = sbase[bk] + lbase[bk] + ernk[i];
            ob[pos] = int2{(rl << 16) | ecol[i], __float_as_int(eval[i])};
        }
    }
}

// Level 2: per-bucket fine counting sort (LDS hist/cursors; writes stay in a ~65KB L2-hot region)
__global__ __launch_bounds__(512) void bsort_kernel(const int* __restrict__ used,
                                                    const int* __restrict__ bbase,
                                                    const int2* __restrict__ bucketed,
                                                    int2* __restrict__ sorted,
                                                    int* __restrict__ rowptr) {
    int a = blockIdx.x / NBKT;
    if (!used[a]) return;
    int b = blockIdx.x % NBKT;
    int base = bbase[a * (NBKT + 1) + b];
    int cnt  = bbase[a * (NBKT + 1) + b + 1] - base;
    int t = threadIdx.x;

    __shared__ int sm[BKT_ROWS];   // hist -> inclusive scan
    __shared__ int cur[BKT_ROWS];  // cursors
    sm[t] = 0;
    __syncthreads();

    const int2* in = bucketed + (size_t)a * NNZ + base;
    for (int i = t; i < cnt; i += 512) {
        atomicAdd(&sm[in[i].x >> 16], 1);
    }
    __syncthreads();
    int own = sm[t];
    for (int off = 1; off < BKT_ROWS; off <<= 1) {
        int v = (t >= off) ? sm[t - off] : 0;
        __syncthreads();
        sm[t] += v;
        __syncthreads();
    }
    int excl = sm[t] - own;
    int row = b * BKT_ROWS + t;
    if (row < N_NODES) rowptr[(size_t)a * (N_NODES + 1) + row] = base + excl;
    cur[t] = excl;
    __syncthreads();

    int2* outp = sorted + (size_t)a * NNZ + base;
    for (int i = t; i < cnt; i += 512) {
        int2 e = in[i];
        int r = e.x >> 16;
        int pos = atomicAdd(&cur[r], 1);
        outp[pos] = int2{e.x & 0xFFFF, e.y};
    }
}

// ---------------- GEMM: h = x @ W + b (bf16 output) ----------------

__global__ __launch_bounds__(256) void gemm_kernel(const float* __restrict__ x,
                                                   const float* __restrict__ W,
                                                   const float* __restrict__ b,
                                                   ushort* __restrict__ h) {
    __shared__ float xs[32][D_PREV]; // 32 KB
    int block_row0 = blockIdx.x * 32;
    int tid = threadIdx.x;
    const float4* x4 = (const float4*)x + (size_t)block_row0 * (D_PREV / 4);
    float4* xs4 = (float4*)xs;
    for (int i = tid; i < 32 * (D_PREV / 4); i += 256) {
        int row = block_row0 + (i >> 6);
        xs4[i] = (row < N_NODES) ? x4[i] : float4{0.f, 0.f, 0.f, 0.f};
    }
    __syncthreads();

    int wave = tid >> 6, lane = tid & 63;
    int r0 = wave * 8;
    float2 bb = *(const float2*)&b[2 * lane];
    float2 acc[8];
#pragma unroll
    for (int r = 0; r < 8; ++r) acc[r] = bb;

    const float2* W2 = (const float2*)W;
    for (int k = 0; k < D_PREV; k += 4) {
        float4 xr[8];
#pragma unroll
        for (int r = 0; r < 8; ++r) xr[r] = *(const float4*)&xs[r0 + r][k];
#pragma unroll
        for (int kk = 0; kk < 4; ++kk) {
            float2 w = W2[(size_t)(k + kk) * 64 + lane];
#pragma unroll
            for (int r = 0; r < 8; ++r) {
                float xv = ((const float*)&xr[r])[kk];
                acc[r].x = fmaf(xv, w.x, acc[r].x);
                acc[r].y = fmaf(xv, w.y, acc[r].y);
            }
        }
    }
#pragma unroll
    for (int r = 0; r < 8; ++r) {
        int row = block_row0 + r0 + r;
        if (row < N_NODES) {
            ushort2 o = {f2bf(acc[r].x), f2bf(acc[r].y)};
            *(ushort2*)&h[(size_t)row * D_HID + 2 * lane] = o;
        }
    }
}

// ---------------- SpMM (CSR gather, one wave per row, bf16 sources) ----------------
// row is wave-uniform: force beg/end scalar (s_load edge lists), batch 8 gathers in flight.

__device__ __forceinline__ void spmm_row(const int* __restrict__ rowptr,
                                         const int2* __restrict__ edges,
                                         int a, int row, int lane,
                                         const uint* __restrict__ src, float2& acc) {
    const int* rp = rowptr + (size_t)a * (N_NODES + 1);
    int beg = __builtin_amdgcn_readfirstlane(rp[row]);
    int end = __builtin_amdgcn_readfirstlane(rp[row + 1]);
    const int2* ed = edges + (size_t)a * NNZ;
    const uint* srcl = src + lane;
    int e = beg;
    for (; e + 8 <= end; e += 8) {
        int2 ev[8];
#pragma unroll
        for (int i = 0; i < 8; ++i) ev[i] = ed[e + i];
        uint u[8];
#pragma unroll
        for (int i = 0; i < 8; ++i) u[i] = srcl[(uint)ev[i].x * 64u];
#pragma unroll
        for (int i = 0; i < 8; ++i) {
            float v = __int_as_float(ev[i].y);
            acc.x = fmaf(v, __uint_as_float(u[i] << 16), acc.x);
            acc.y = fmaf(v, __uint_as_float(u[i] & 0xFFFF0000u), acc.y);
        }
    }
    if (e + 4 <= end) {
        int2 ev[4];
#pragma unroll
        for (int i = 0; i < 4; ++i) ev[i] = ed[e + i];
        uint u[4];
#pragma unroll
        for (int i = 0; i < 4; ++i) u[i] = srcl[(uint)ev[i].x * 64u];
#pragma unroll
        for (int i = 0; i < 4; ++i) {
            float v = __int_as_float(ev[i].y);
            acc.x = fmaf(v, __uint_as_float(u[i] << 16), acc.x);
            acc.y = fmaf(v, __uint_as_float(u[i] & 0xFFFF0000u), acc.y);
        }
        e += 4;
    }
    for (; e < end; ++e) {
        int2 e0 = ed[e];
        uint u0 = srcl[(uint)e0.x * 64u];
        float v0 = __int_as_float(e0.y);
        acc.x = fmaf(v0, __uint_as_float(u0 << 16), acc.x);
        acc.y = fmaf(v0, __uint_as_float(u0 & 0xFFFF0000u), acc.y);
    }
}

__global__ __launch_bounds__(256) void spmm1_kernel(const int* __restrict__ rowptr,
                                                    const int2* __restrict__ edges,
                                                    const int* __restrict__ seq,
                                                    const uint* __restrict__ h,
                                                    ushort* __restrict__ s1) {
    int row = blockIdx.x * 4 + (threadIdx.x >> 6);
    if (row >= N_NODES) return;
    int lane = threadIdx.x & 63;
    float2 acc = {0.f, 0.f};
    spmm_row(rowptr, edges, seq[0], row, lane, h, acc);
    ushort2 o = {f2bf(acc.x), f2bf(acc.y)};
    *(ushort2*)&s1[(size_t)row * D_HID + 2 * lane] = o;
}

__global__ __launch_bounds__(256) void spmm2_kernel(const int* __restrict__ rowptr,
                                                    const int2* __restrict__ edges,
                                                    const int* __restrict__ seq,
                                                    const int* __restrict__ res,
                                                    const uint* __restrict__ s1,
                                                    const uint* __restrict__ h,
                                                    ushort* __restrict__ s2) {
    int row = blockIdx.x * 4 + (threadIdx.x >> 6);
    if (row >= N_NODES) return;
    int lane = threadIdx.x & 63;
    float2 acc = {0.f, 0.f};
    spmm_row(rowptr, edges, seq[1], row, lane, s1, acc);
    spmm_row(rowptr, edges, res[0], row, lane, h, acc);
    ushort2 o = {f2bf(acc.x), f2bf(acc.y)};
    *(ushort2*)&s2[(size_t)row * D_HID + 2 * lane] = o;
}

__global__ __launch_bounds__(256) void spmm3_ln_gelu_kernel(const int* __restrict__ rowptr,
                                                            const int2* __restrict__ edges,
                                                            const int* __restrict__ seq,
                                                            const int* __restrict__ res,
                                                            const uint* __restrict__ s2,
                                                            const uint* __restrict__ h,
                                                            const uint* __restrict__ s1,
                                                            const float* __restrict__ gamma,
                                                            const float* __restrict__ beta,
                                                            float* __restrict__ out) {
    int row = blockIdx.x * 4 + (threadIdx.x >> 6);
    if (row >= N_NODES) return;
    int lane = threadIdx.x & 63;
    float2 acc = {0.f, 0.f};
    spmm_row(rowptr, edges, seq[2], row, lane, s2, acc);
    spmm_row(rowptr, edges, res[1], row, lane, h, acc);
    spmm_row(rowptr, edges, res[2], row, lane, s1, acc);

    float s = acc.x + acc.y;
    float sq = acc.x * acc.x + acc.y * acc.y;
#pragma unroll
    for (int m = 1; m < 64; m <<= 1) {
        s += __shfl_xor(s, m);
        sq += __shfl_xor(sq, m);
    }
    float mean = s * (1.0f / D_HID);
    float var = fmaxf(sq * (1.0f / D_HID) - mean * mean, 0.f);
    float inv = rsqrtf(var + LN_EPS);
    float2 g = *(const float2*)&gamma[2 * lane];
    float2 bt = *(const float2*)&beta[2 * lane];
    float n0 = (acc.x - mean) * inv * g.x + bt.x;
    float n1 = (acc.y - mean) * inv * g.y + bt.y;
    const float kInvSqrt2 = 0.70710678118654752f;
    float2 o;
    o.x = 0.5f * n0 * (1.f + erff(n0 * kInvSqrt2));
    o.y = 0.5f * n1 * (1.f + erff(n1 * kInvSqrt2));
    *(float2*)&out[(size_t)row * D_HID + 2 * lane] = o;
}

// ---------------- launch ----------------

extern "C" void kernel_launch(void* const* d_in, const int* in_sizes, int n_in,
                              void* d_out, int out_size, void* d_ws, size_t ws_size,
                              hipStream_t stream) {
    const float* x       = (const float*)d_in[0];
    const int*   adjRows = (const int*)d_in[1];
    const int*   adjCols = (const int*)d_in[2];
    const float* adjVals = (const float*)d_in[3];
    const int*   seq     = (const int*)d_in[4];
    const int*   res     = (const int*)d_in[5];
    const float* W       = (const float*)d_in[6];
    const float* b       = (const float*)d_in[7];
    const float* gamma   = (const float*)d_in[8];
    const float* beta    = (const float*)d_in[9];
    float* out = (float*)d_out;

    if (ws_size < WS_TOTAL) return;

    char* ws = (char*)d_ws;
    int*    used     = (int*)(ws + USED_OFF);
    int*    bcnt     = (int*)(ws + BCNT_OFF);
    int*    gcur     = (int*)(ws + GCUR_OFF);
    int*    bbase    = (int*)(ws + BBASE_OFF);
    int*    rowptr   = (int*)(ws + ROWPTR_OFF);
    int2*   bucketed = (int2*)(ws + BUCK_OFF);
    int2*   sorted   = (int2*)(ws + SORT_OFF);
    ushort* h        = (ushort*)(ws + H_OFF);
    ushort* s1       = (ushort*)(ws + S1_OFF);
    ushort* s2       = (ushort*)(ws + S2_OFF);

    gemm_kernel<<<(N_NODES + 31) / 32, 256, 0, stream>>>(x, W, b, h);

    used_kernel<<<1, 64, 0, stream>>>(seq, res, used);
    hipMemsetAsync(bcnt, 0, (size_t)2 * N_ADJ * NBKT * sizeof(int), stream); // bcnt + gcur
    bhist_kernel<<<N_ADJ * BPA, BLK, 0, stream>>>(adjRows, used, bcnt);
    bscan_kernel<<<N_ADJ, 64, 0, stream>>>(used, bcnt, bbase, rowptr);
    bscatter_kernel<<<N_ADJ * BPA, BLK, 0, stream>>>(adjRows, adjCols, adjVals, used,
                                                     bbase, gcur, bucketed);
    bsort_kernel<<<N_ADJ * NBKT, 512, 0, stream>>>(used, bbase, bucketed, sorted, rowptr);

    spmm1_kernel<<<(N_NODES + 3) / 4, 256, 0, stream>>>(rowptr, sorted, seq, (const uint*)h, s1);
    spmm2_kernel<<<(N_NODES + 3) / 4, 256, 0, stream>>>(rowptr, sorted, seq, res,
                                                        (const uint*)s1, (const uint*)h, s2);
    spmm3_ln_gelu_kernel<<<(N_NODES + 3) / 4, 256, 0, stream>>>(rowptr, sorted, seq, res,
                                                                (const uint*)s2, (const uint*)h,
                                                                (const uint*)s1, gamma, beta, out);
}

// Round 5
// 286.792 us; speedup vs baseline: 3.2801x; 1.1486x over previous
//
#include <hip/hip_runtime.h>

#define N_NODES 50000
#define N_ADJ 6
#define NNZ 800000
#define D_PREV 256
#define D_HID 128
#define LN_EPS 1e-5f

typedef unsigned int uint;
typedef unsigned short ushort;

typedef short s16x8 __attribute__((ext_vector_type(8)));
typedef float f32x4 __attribute__((ext_vector_type(4)));

static constexpr int EPT = 8;
static constexpr int BLK = 256;
static constexpr int BPA = (NNZ + BLK * EPT - 1) / (BLK * EPT); // 391

static constexpr int BKT_SHIFT = 9;
static constexpr int BKT_ROWS = 1 << BKT_SHIFT;                       // 512
static constexpr int NBKT = (N_NODES + BKT_ROWS - 1) / BKT_ROWS;      // 98

static constexpr size_t WP_ELEMS = 8 * 8 * 64 * 8; // t,s,lane,j  (bf16 of W) = 32768

static constexpr size_t align256(size_t x) { return (x + 255) & ~(size_t)255; }
static constexpr size_t USED_OFF   = 0;
static constexpr size_t BCNT_OFF   = align256(USED_OFF + N_ADJ * sizeof(int));
static constexpr size_t GCUR_OFF   = BCNT_OFF + (size_t)N_ADJ * NBKT * sizeof(int); // adjacent -> one memset
static constexpr size_t BBASE_OFF  = align256(GCUR_OFF + (size_t)N_ADJ * NBKT * sizeof(int));
static constexpr size_t ROWPTR_OFF = align256(BBASE_OFF + (size_t)N_ADJ * (NBKT + 1) * sizeof(int));
static constexpr size_t BUCK_OFF   = align256(ROWPTR_OFF + (size_t)N_ADJ * (N_NODES + 1) * sizeof(int));
static constexpr size_t SORT_OFF   = align256(BUCK_OFF + (size_t)N_ADJ * NNZ * sizeof(int2));
static constexpr size_t WP_OFF     = align256(SORT_OFF + (size_t)N_ADJ * NNZ * sizeof(int2));
static constexpr size_t H_OFF      = align256(WP_OFF + WP_ELEMS * sizeof(ushort));
static constexpr size_t S1_OFF     = align256(H_OFF + (size_t)N_NODES * D_HID * sizeof(ushort));
static constexpr size_t S2_OFF     = align256(S1_OFF + (size_t)N_NODES * D_HID * sizeof(ushort));
static constexpr size_t WS_TOTAL   = S2_OFF + (size_t)N_NODES * D_HID * sizeof(ushort);

__device__ __forceinline__ ushort f2bf(float f) {
    uint u = __float_as_uint(f);
    uint r = (u + 0x7FFFu + ((u >> 16) & 1u)) >> 16;
    return (ushort)r;
}

// ---------------- preprocessing ----------------

__global__ void used_kernel(const int* __restrict__ seq, const int* __restrict__ res,
                            int* __restrict__ used) {
    int t = threadIdx.x;
    if (t < N_ADJ) used[t] = 0;
    __syncthreads();
    if (t == 0) {
        for (int i = 0; i < 3; ++i) used[seq[i]] = 1;
        for (int i = 0; i < 3; ++i) used[res[i]] = 1;
    }
}

// Level 1a: coarse bucket histogram (LDS-aggregated)
__global__ __launch_bounds__(BLK) void bhist_kernel(const int* __restrict__ rows,
                                                    const int* __restrict__ used,
                                                    int* __restrict__ bcnt) {
    int a = blockIdx.x / BPA;
    if (!used[a]) return;
    __shared__ int lcnt[NBKT];
    int t = threadIdx.x;
    if (t < NBKT) lcnt[t] = 0;
    __syncthreads();
    int blk = blockIdx.x % BPA;
    int base = blk * (BLK * EPT) + t;
    const int* r = rows + (size_t)a * NNZ;
#pragma unroll
    for (int i = 0; i < EPT; ++i) {
        int e = base + i * BLK;
        if (e < NNZ) atomicAdd(&lcnt[r[e] >> BKT_SHIFT], 1);
    }
    __syncthreads();
    if (t < NBKT) atomicAdd(&bcnt[a * NBKT + t], lcnt[t]);
}

// Level 1b: tiny scan of 98 bucket counts per adjacency
__global__ void bscan_kernel(const int* __restrict__ used,
                             const int* __restrict__ bcnt,
                             int* __restrict__ bbase,
                             int* __restrict__ rowptr) {
    int a = blockIdx.x;
    if (!used[a]) return;
    if (threadIdx.x == 0) {
        int run = 0;
        for (int k = 0; k < NBKT; ++k) {
            bbase[a * (NBKT + 1) + k] = run;
            run += bcnt[a * NBKT + k];
        }
        bbase[a * (NBKT + 1) + NBKT] = run;           // == NNZ
        rowptr[(size_t)a * (N_NODES + 1) + N_NODES] = run;
    }
}

// Level 1c: scatter edges into coarse buckets (exact regions, per-block runs)
__global__ __launch_bounds__(BLK) void bscatter_kernel(const int* __restrict__ rows,
                                                       const int* __restrict__ cols,
                                                       const float* __restrict__ vals,
                                                       const int* __restrict__ used,
                                                       const int* __restrict__ bbase,
                                                       int* __restrict__ gcur,
                                                       int2* __restrict__ bucketed) {
    int a = blockIdx.x / BPA;
    if (!used[a]) return;
    __shared__ int lcnt[NBKT];
    __shared__ int lbase[NBKT];
    __shared__ int sbase[NBKT];
    int t = threadIdx.x;
    if (t < NBKT) {
        lcnt[t] = 0;
        sbase[t] = bbase[a * (NBKT + 1) + t];
    }
    __syncthreads();
    int blk = blockIdx.x % BPA;
    int base = blk * (BLK * EPT) + t;
    const int* rr = rows + (size_t)a * NNZ;
    const int* cc = cols + (size_t)a * NNZ;
    const float* vv = vals + (size_t)a * NNZ;
    int ebk[EPT], ernk[EPT], ecol[EPT];
    float eval[EPT];
#pragma unroll
    for (int i = 0; i < EPT; ++i) {
        int e = base + i * BLK;
        ebk[i] = -1;
        if (e < NNZ) {
            int row = rr[e];
            ecol[i] = cc[e];
            eval[i] = vv[e];
            int bk = row >> BKT_SHIFT;
            ebk[i] = (bk << 16) | (row & (BKT_ROWS - 1));
            ernk[i] = atomicAdd(&lcnt[bk], 1);
        }
    }
    __syncthreads();
    if (t < NBKT) lbase[t] = atomicAdd(&gcur[a * NBKT + t], lcnt[t]);
    __syncthreads();
    int2* ob = bucketed + (size_t)a * NNZ;
#pragma unroll
    for (int i = 0; i < EPT; ++i) {
        if (ebk[i] >= 0) {
            int bk = ebk[i] >> 16;
            int rl = ebk[i] & 0xFFFF;
            int pos = sbase[bk] + lbase[bk] + ernk[i];
            ob[pos] = int2{(rl << 16) | ecol[i], __float_as_int(eval[i])};
        }
    }
}

// Level 2: per-bucket fine counting sort (LDS hist/cursors; writes stay in a ~65KB L2-hot region)
__global__ __launch_bounds__(512) void bsort_kernel(const int* __restrict__ used,
                                                    const int* __restrict__ bbase,
                                                    const int2* __restrict__ bucketed,
                                                    int2* __restrict__ sorted,
                                                    int* __restrict__ rowptr) {
    int a = blockIdx.x / NBKT;
    if (!used[a]) return;
    int b = blockIdx.x % NBKT;
    int base = bbase[a * (NBKT + 1) + b];
    int cnt  = bbase[a * (NBKT + 1) + b + 1] - base;
    int t = threadIdx.x;

    __shared__ int sm[BKT_ROWS];   // hist -> inclusive scan
    __shared__ int cur[BKT_ROWS];  // cursors
    sm[t] = 0;
    __syncthreads();

    const int2* in = bucketed + (size_t)a * NNZ + base;
    for (int i = t; i < cnt; i += 512) {
        atomicAdd(&sm[in[i].x >> 16], 1);
    }
    __syncthreads();
    int own = sm[t];
    for (int off = 1; off < BKT_ROWS; off <<= 1) {
        int v = (t >= off) ? sm[t - off] : 0;
        __syncthreads();
        sm[t] += v;
        __syncthreads();
    }
    int excl = sm[t] - own;
    int row = b * BKT_ROWS + t;
    if (row < N_NODES) rowptr[(size_t)a * (N_NODES + 1) + row] = base + excl;
    cur[t] = excl;
    __syncthreads();

    int2* outp = sorted + (size_t)a * NNZ + base;
    for (int i = t; i < cnt; i += 512) {
        int2 e = in[i];
        int r = e.x >> 16;
        int pos = atomicAdd(&cur[r], 1);
        outp[pos] = int2{e.x & 0xFFFF, e.y};
    }
}

// ---------------- W pack: f32 [256][128] -> bf16 B-fragment order ----------------
// Wp[(((t*8)+s)*64 + l)*8 + j] = bf16(W[k][n]),  k = s*32 + (l>>4)*8 + j,  n = t*16 + (l&15)

__global__ __launch_bounds__(256) void packw_kernel(const float* __restrict__ W,
                                                    ushort* __restrict__ Wp) {
    int gid = blockIdx.x * 256 + threadIdx.x; // 0..4095 = (t,s,l)
    int l = gid & 63;
    int ts = gid >> 6;
    int s = ts & 7, t = ts >> 3;
    int kb = s * 32 + (l >> 4) * 8;
    int n = t * 16 + (l & 15);
    ushort* o = Wp + (size_t)gid * 8;
#pragma unroll
    for (int j = 0; j < 8; ++j) {
        o[j] = f2bf(W[(size_t)(kb + j) * D_HID + n]);
    }
}

// ---------------- GEMM: h = bf16(x) @ bf16(W) + b via MFMA ----------------
// Block = 4 waves; wave w owns rows [blk*64 + w*16, +16) x all 128 cols.
// A-frag: lane l holds x[m0 + (l&15)][k=(l>>4)*8 .. +8) converted to bf16.
// acc[t] initialized with bias (C-in of first MFMA).

__global__ __launch_bounds__(256) void gemm_mfma_kernel(const float* __restrict__ x,
                                                        const ushort* __restrict__ Wp,
                                                        const float* __restrict__ b,
                                                        ushort* __restrict__ h) {
    int tid = threadIdx.x;
    int w = tid >> 6, l = tid & 63;
    int m0 = blockIdx.x * 64 + w * 16;
    int arow = m0 + (l & 15);
    bool rowok = arow < N_NODES;
    const float* xr = x + (size_t)arow * D_PREV + (l >> 4) * 8;

    float bb = b[((tid & 63) & 15) + 0 * 16]; // placeholder, real init below
    f32x4 acc[8];
#pragma unroll
    for (int t = 0; t < 8; ++t) {
        float bv = b[t * 16 + (l & 15)];
        acc[t] = f32x4{bv, bv, bv, bv};
    }
    (void)bb;

    const s16x8* wp = (const s16x8*)Wp;
#pragma unroll
    for (int s = 0; s < 8; ++s) {
        s16x8 af = (s16x8)0;
        if (rowok) {
            float4 lo = *(const float4*)(xr + s * 32);
            float4 hi = *(const float4*)(xr + s * 32 + 4);
            af[0] = (short)f2bf(lo.x); af[1] = (short)f2bf(lo.y);
            af[2] = (short)f2bf(lo.z); af[3] = (short)f2bf(lo.w);
            af[4] = (short)f2bf(hi.x); af[5] = (short)f2bf(hi.y);
            af[6] = (short)f2bf(hi.z); af[7] = (short)f2bf(hi.w);
        }
#pragma unroll
        for (int t = 0; t < 8; ++t) {
            s16x8 bf = wp[(t * 8 + s) * 64 + l];
            acc[t] = __builtin_amdgcn_mfma_f32_16x16x32_bf16(af, bf, acc[t], 0, 0, 0);
        }
    }

    // C/D layout: col = lane&15, row = (lane>>4)*4 + reg   [m89 verified]
    int crow0 = m0 + (l >> 4) * 4;
#pragma unroll
    for (int t = 0; t < 8; ++t) {
        int col = t * 16 + (l & 15);
#pragma unroll
        for (int r = 0; r < 4; ++r) {
            int row = crow0 + r;
            if (row < N_NODES) h[(size_t)row * D_HID + col] = f2bf(acc[t][r]);
        }
    }
}

// ---------------- SpMM (CSR gather, one wave per row, bf16 sources) ----------------
// row is wave-uniform: force beg/end scalar (s_load edge lists), batch 8 gathers in flight.

__device__ __forceinline__ void spmm_row(const int* __restrict__ rowptr,
                                         const int2* __restrict__ edges,
                                         int a, int row, int lane,
                                         const uint* __restrict__ src, float2& acc) {
    const int* rp = rowptr + (size_t)a * (N_NODES + 1);
    int beg = __builtin_amdgcn_readfirstlane(rp[row]);
    int end = __builtin_amdgcn_readfirstlane(rp[row + 1]);
    const int2* ed = edges + (size_t)a * NNZ;
    const uint* srcl = src + lane;
    int e = beg;
    for (; e + 8 <= end; e += 8) {
        int2 ev[8];
#pragma unroll
        for (int i = 0; i < 8; ++i) ev[i] = ed[e + i];
        uint u[8];
#pragma unroll
        for (int i = 0; i < 8; ++i) u[i] = srcl[(uint)ev[i].x * 64u];
#pragma unroll
        for (int i = 0; i < 8; ++i) {
            float v = __int_as_float(ev[i].y);
            acc.x = fmaf(v, __uint_as_float(u[i] << 16), acc.x);
            acc.y = fmaf(v, __uint_as_float(u[i] & 0xFFFF0000u), acc.y);
        }
    }
    if (e + 4 <= end) {
        int2 ev[4];
#pragma unroll
        for (int i = 0; i < 4; ++i) ev[i] = ed[e + i];
        uint u[4];
#pragma unroll
        for (int i = 0; i < 4; ++i) u[i] = srcl[(uint)ev[i].x * 64u];
#pragma unroll
        for (int i = 0; i < 4; ++i) {
            float v = __int_as_float(ev[i].y);
            acc.x = fmaf(v, __uint_as_float(u[i] << 16), acc.x);
            acc.y = fmaf(v, __uint_as_float(u[i] & 0xFFFF0000u), acc.y);
        }
        e += 4;
    }
    for (; e < end; ++e) {
        int2 e0 = ed[e];
        uint u0 = srcl[(uint)e0.x * 64u];
        float v0 = __int_as_float(e0.y);
        acc.x = fmaf(v0, __uint_as_float(u0 << 16), acc.x);
        acc.y = fmaf(v0, __uint_as_float(u0 & 0xFFFF0000u), acc.y);
    }
}

__global__ __launch_bounds__(256) void spmm1_kernel(const int* __restrict__ rowptr,
                                                    const int2* __restrict__ edges,
                                                    const int* __restrict__ seq,
                                                    const uint* __restrict__ h,
                                                    ushort* __restrict__ s1) {
    int row = blockIdx.x * 4 + (threadIdx.x >> 6);
    if (row >= N_NODES) return;
    int lane = threadIdx.x & 63;
    float2 acc = {0.f, 0.f};
    spmm_row(rowptr, edges, seq[0], row, lane, h, acc);
    ushort2 o = {f2bf(acc.x), f2bf(acc.y)};
    *(ushort2*)&s1[(size_t)row * D_HID + 2 * lane] = o;
}

__global__ __launch_bounds__(256) void spmm2_kernel(const int* __restrict__ rowptr,
                                                    const int2* __restrict__ edges,
                                                    const int* __restrict__ seq,
                                                    const int* __restrict__ res,
                                                    const uint* __restrict__ s1,
                                                    const uint* __restrict__ h,
                                                    ushort* __restrict__ s2) {
    int row = blockIdx.x * 4 + (threadIdx.x >> 6);
    if (row >= N_NODES) return;
    int lane = threadIdx.x & 63;
    float2 acc = {0.f, 0.f};
    spmm_row(rowptr, edges, seq[1], row, lane, s1, acc);
    spmm_row(rowptr, edges, res[0], row, lane, h, acc);
    ushort2 o = {f2bf(acc.x), f2bf(acc.y)};
    *(ushort2*)&s2[(size_t)row * D_HID + 2 * lane] = o;
}

__global__ __launch_bounds__(256) void spmm3_ln_gelu_kernel(const int* __restrict__ rowptr,
                                                            const int2* __restrict__ edges,
                                                            const int* __restrict__ seq,
                                                            const int* __restrict__ res,
                                                            const uint* __restrict__ s2,
                                                            const uint* __restrict__ h,
                                                            const uint* __restrict__ s1,
                                                            const float* __restrict__ gamma,
                                                            const float* __restrict__ beta,
                                                            float* __restrict__ out) {
    int row = blockIdx.x * 4 + (threadIdx.x >> 6);
    if (row >= N_NODES) return;
    int lane = threadIdx.x & 63;
    float2 acc = {0.f, 0.f};
    spmm_row(rowptr, edges, seq[2], row, lane, s2, acc);
    spmm_row(rowptr, edges, res[1], row, lane, h, acc);
    spmm_row(rowptr, edges, res[2], row, lane, s1, acc);

    float s = acc.x + acc.y;
    float sq = acc.x * acc.x + acc.y * acc.y;
#pragma unroll
    for (int m = 1; m < 64; m <<= 1) {
        s += __shfl_xor(s, m);
        sq += __shfl_xor(sq, m);
    }
    float mean = s * (1.0f / D_HID);
    float var = fmaxf(sq * (1.0f / D_HID) - mean * mean, 0.f);
    float inv = rsqrtf(var + LN_EPS);
    float2 g = *(const float2*)&gamma[2 * lane];
    float2 bt = *(const float2*)&beta[2 * lane];
    float n0 = (acc.x - mean) * inv * g.x + bt.x;
    float n1 = (acc.y - mean) * inv * g.y + bt.y;
    const float kInvSqrt2 = 0.70710678118654752f;
    float2 o;
    o.x = 0.5f * n0 * (1.f + erff(n0 * kInvSqrt2));
    o.y = 0.5f * n1 * (1.f + erff(n1 * kInvSqrt2));
    *(float2*)&out[(size_t)row * D_HID + 2 * lane] = o;
}

// ---------------- launch ----------------

extern "C" void kernel_launch(void* const* d_in, const int* in_sizes, int n_in,
                              void* d_out, int out_size, void* d_ws, size_t ws_size,
                              hipStream_t stream) {
    const float* x       = (const float*)d_in[0];
    const int*   adjRows = (const int*)d_in[1];
    const int*   adjCols = (const int*)d_in[2];
    const float* adjVals = (const float*)d_in[3];
    const int*   seq     = (const int*)d_in[4];
    const int*   res     = (const int*)d_in[5];
    const float* W       = (const float*)d_in[6];
    const float* b       = (const float*)d_in[7];
    const float* gamma   = (const float*)d_in[8];
    const float* beta    = (const float*)d_in[9];
    float* out = (float*)d_out;

    if (ws_size < WS_TOTAL) return;

    char* ws = (char*)d_ws;
    int*    used     = (int*)(ws + USED_OFF);
    int*    bcnt     = (int*)(ws + BCNT_OFF);
    int*    gcur     = (int*)(ws + GCUR_OFF);
    int*    bbase    = (int*)(ws + BBASE_OFF);
    int*    rowptr   = (int*)(ws + ROWPTR_OFF);
    int2*   bucketed = (int2*)(ws + BUCK_OFF);
    int2*   sorted   = (int2*)(ws + SORT_OFF);
    ushort* Wp       = (ushort*)(ws + WP_OFF);
    ushort* h        = (ushort*)(ws + H_OFF);
    ushort* s1       = (ushort*)(ws + S1_OFF);
    ushort* s2       = (ushort*)(ws + S2_OFF);

    packw_kernel<<<16, 256, 0, stream>>>(W, Wp);
    gemm_mfma_kernel<<<(N_NODES + 63) / 64, 256, 0, stream>>>(x, Wp, b, h);

    used_kernel<<<1, 64, 0, stream>>>(seq, res, used);
    hipMemsetAsync(bcnt, 0, (size_t)2 * N_ADJ * NBKT * sizeof(int), stream); // bcnt + gcur
    bhist_kernel<<<N_ADJ * BPA, BLK, 0, stream>>>(adjRows, used, bcnt);
    bscan_kernel<<<N_ADJ, 64, 0, stream>>>(used, bcnt, bbase, rowptr);
    bscatter_kernel<<<N_ADJ * BPA, BLK, 0, stream>>>(adjRows, adjCols, adjVals, used,
                                                     bbase, gcur, bucketed);
    bsort_kernel<<<N_ADJ * NBKT, 512, 0, stream>>>(used, bbase, bucketed, sorted, rowptr);

    spmm1_kernel<<<(N_NODES + 3) / 4, 256, 0, stream>>>(rowptr, sorted, seq, (const uint*)h, s1);
    spmm2_kernel<<<(N_NODES + 3) / 4, 256, 0, stream>>>(rowptr, sorted, seq, res,
                                                        (const uint*)s1, (const uint*)h, s2);
    spmm3_ln_gelu_kernel<<<(N_NODES + 3) / 4, 256, 0, stream>>>(rowptr, sorted, seq, res,
                                                                (const uint*)s2, (const uint*)h,
                                                                (const uint*)s1, gamma, beta, out);
}

// Round 6
// 259.067 us; speedup vs baseline: 3.6311x; 1.1070x over previous
//
#include <hip/hip_runtime.h>

#define N_NODES 50000
#define N_ADJ 6
#define NNZ 800000
#define D_PREV 256
#define D_HID 128
#define LN_EPS 1e-5f

typedef unsigned int uint;
typedef unsigned short ushort;

typedef short s16x8 __attribute__((ext_vector_type(8)));
typedef float f32x4 __attribute__((ext_vector_type(4)));

static constexpr int EPT = 8;
static constexpr int BLK = 256;
static constexpr int BPA = (NNZ + BLK * EPT - 1) / (BLK * EPT); // 391

static constexpr int BKT_SHIFT = 9;
static constexpr int BKT_ROWS = 1 << BKT_SHIFT;                       // 512
static constexpr int NBKT = (N_NODES + BKT_ROWS - 1) / BKT_ROWS;      // 98

// Bucket counts ~ Binomial(800k, 512/50000): mean 8192, sigma ~90.
static constexpr int CAP_B = 9216;   // mean + 11 sigma (overflow clamped -> loud failure)
static constexpr int CAP_S = 13312;  // CAP_B + max pad (512 rows * 7) + margin

static constexpr size_t WP_ELEMS = 8 * 8 * 64 * 8; // 32768 bf16 of W

static constexpr size_t align256(size_t x) { return (x + 255) & ~(size_t)255; }
static constexpr size_t USED_OFF = 0;
static constexpr size_t GCUR_OFF = align256(USED_OFF + N_ADJ * sizeof(int));
static constexpr size_t RR_OFF   = align256(GCUR_OFF + (size_t)N_ADJ * NBKT * sizeof(int));
static constexpr size_t BE_OFF   = align256(RR_OFF + (size_t)N_ADJ * N_NODES * sizeof(int2));
static constexpr size_t BR_OFF   = align256(BE_OFF + (size_t)N_ADJ * NBKT * CAP_B * sizeof(uint));
static constexpr size_t SO_OFF   = align256(BR_OFF + (size_t)N_ADJ * NBKT * CAP_B * sizeof(ushort));
static constexpr size_t WP_OFF   = align256(SO_OFF + (size_t)N_ADJ * NBKT * CAP_S * sizeof(uint));
static constexpr size_t H_OFF    = align256(WP_OFF + WP_ELEMS * sizeof(ushort));
static constexpr size_t S1_OFF   = align256(H_OFF + (size_t)N_NODES * D_HID * sizeof(ushort));
static constexpr size_t S2_OFF   = align256(S1_OFF + (size_t)N_NODES * D_HID * sizeof(ushort));
static constexpr size_t WS_TOTAL = S2_OFF + (size_t)N_NODES * D_HID * sizeof(ushort);

__device__ __forceinline__ ushort f2bf(float f) {
    uint u = __float_as_uint(f);
    uint r = (u + 0x7FFFu + ((u >> 16) & 1u)) >> 16;
    return (ushort)r;
}

// ---------------- preprocessing ----------------

// used flags + zero bucket cursors (replaces memsetAsync)
__global__ __launch_bounds__(1024) void used_kernel(const int* __restrict__ seq,
                                                    const int* __restrict__ res,
                                                    int* __restrict__ used,
                                                    int* __restrict__ gcur) {
    int t = threadIdx.x;
    if (t < N_ADJ) used[t] = 0;
    for (int i = t; i < N_ADJ * NBKT; i += 1024) gcur[i] = 0;
    __syncthreads();
    if (t == 0) {
        for (int i = 0; i < 3; ++i) used[seq[i]] = 1;
        for (int i = 0; i < 3; ++i) used[res[i]] = 1;
    }
}

// Level 1: scatter edges into fixed-capacity coarse buckets.
// bedge = (col<<16)|bf16(val), brow = local row (0..511).
__global__ __launch_bounds__(BLK) void bscatter_kernel(const int* __restrict__ rows,
                                                       const int* __restrict__ cols,
                                                       const float* __restrict__ vals,
                                                       const int* __restrict__ used,
                                                       int* __restrict__ gcur,
                                                       uint* __restrict__ bedge,
                                                       ushort* __restrict__ brow) {
    int a = blockIdx.x / BPA;
    if (!used[a]) return;
    __shared__ int lcnt[NBKT];
    __shared__ int lbase[NBKT];
    int t = threadIdx.x;
    if (t < NBKT) lcnt[t] = 0;
    __syncthreads();
    int base = (blockIdx.x % BPA) * (BLK * EPT) + t;
    const int* rr = rows + (size_t)a * NNZ;
    const int* cc = cols + (size_t)a * NNZ;
    const float* vv = vals + (size_t)a * NNZ;
    int erow[EPT], ernk[EPT];
    uint eg[EPT];
#pragma unroll
    for (int i = 0; i < EPT; ++i) {
        int e = base + i * BLK;
        erow[i] = -1;
        if (e < NNZ) {
            int row = rr[e];
            erow[i] = row;
            eg[i] = ((uint)cc[e] << 16) | (uint)f2bf(vv[e]);
            ernk[i] = atomicAdd(&lcnt[row >> BKT_SHIFT], 1);
        }
    }
    __syncthreads();
    if (t < NBKT) lbase[t] = atomicAdd(&gcur[a * NBKT + t], lcnt[t]);
    __syncthreads();
    uint* be = bedge + (size_t)a * NBKT * CAP_B;
    ushort* br = brow + (size_t)a * NBKT * CAP_B;
#pragma unroll
    for (int i = 0; i < EPT; ++i) {
        if (erow[i] >= 0) {
            int bk = erow[i] >> BKT_SHIFT;
            int pos = lbase[bk] + ernk[i];
            if (pos < CAP_B) { // overflow guard (loud failure via validation)
                size_t slot = (size_t)bk * CAP_B + pos;
                be[slot] = eg[i];
                br[slot] = (ushort)(erow[i] & (BKT_ROWS - 1));
            }
        }
    }
}

// Level 2: per-bucket counting sort with per-row pad-to-8 (null edges).
// rowrange[row] = {beg, beg+padded} absolute into sorted (bucket-strided CAP_S).
__global__ __launch_bounds__(512) void bsort_kernel(const int* __restrict__ used,
                                                    const int* __restrict__ gcur,
                                                    const uint* __restrict__ bedge,
                                                    const ushort* __restrict__ brow,
                                                    uint* __restrict__ sorted,
                                                    int2* __restrict__ rowrange) {
    int a = blockIdx.x / NBKT;
    if (!used[a]) return;
    int b = blockIdx.x % NBKT;
    int cnt = gcur[a * NBKT + b];
    if (cnt > CAP_B) cnt = CAP_B;
    int t = threadIdx.x;

    __shared__ int sm[BKT_ROWS];
    __shared__ int cur[BKT_ROWS];
    __shared__ int wsum[8];
    sm[t] = 0;
    __syncthreads();

    const uint* be = bedge + (size_t)a * NBKT * CAP_B + (size_t)b * CAP_B;
    const ushort* br = brow + (size_t)a * NBKT * CAP_B + (size_t)b * CAP_B;
    for (int i = t; i < cnt; i += 512) atomicAdd(&sm[br[i]], 1);
    __syncthreads();

    int own = sm[t];
    int pad = (own + 7) & ~7;
    // wave-structured exclusive scan of pad
    int lane = t & 63, w = t >> 6;
    int v = pad;
#pragma unroll
    for (int o = 1; o < 64; o <<= 1) {
        int u = __shfl_up(v, o);
        if (lane >= o) v += u;
    }
    if (lane == 63) wsum[w] = v;
    __syncthreads();
    int woff = 0;
#pragma unroll
    for (int k = 0; k < 8; ++k)
        if (k < w) woff += wsum[k];
    int excl = woff + v - pad;

    int row = b * BKT_ROWS + t;
    int sbase = b * CAP_S;
    if (row < N_NODES)
        rowrange[(size_t)a * N_NODES + row] = int2{sbase + excl, sbase + excl + pad};
    cur[t] = excl;
    __syncthreads();

    uint* so = sorted + (size_t)a * NBKT * CAP_S;
    for (int i = t; i < cnt; i += 512) {
        int r = br[i];
        int p = atomicAdd(&cur[r], 1);
        so[sbase + p] = be[i];
    }
    // fill pad slots with null edges (col 0, val 0): disjoint from scatter slots
    for (int p = own; p < pad; ++p) so[sbase + excl + p] = 0u;
}

// ---------------- W pack: f32 [256][128] -> bf16 B-fragment order ----------------

__global__ __launch_bounds__(256) void packw_kernel(const float* __restrict__ W,
                                                    ushort* __restrict__ Wp) {
    int gid = blockIdx.x * 256 + threadIdx.x; // (t,s,l)
    int l = gid & 63;
    int ts = gid >> 6;
    int s = ts & 7, t = ts >> 3;
    int kb = s * 32 + (l >> 4) * 8;
    int n = t * 16 + (l & 15);
    ushort* o = Wp + (size_t)gid * 8;
#pragma unroll
    for (int j = 0; j < 8; ++j) o[j] = f2bf(W[(size_t)(kb + j) * D_HID + n]);
}

// ---------------- GEMM: h = bf16(x) @ bf16(W) + b via MFMA ----------------

__global__ __launch_bounds__(256) void gemm_mfma_kernel(const float* __restrict__ x,
                                                        const ushort* __restrict__ Wp,
                                                        const float* __restrict__ b,
                                                        ushort* __restrict__ h) {
    int tid = threadIdx.x;
    int w = tid >> 6, l = tid & 63;
    int m0 = blockIdx.x * 64 + w * 16;
    int arow = m0 + (l & 15);
    bool rowok = arow < N_NODES;
    const float* xr = x + (size_t)arow * D_PREV + (l >> 4) * 8;

    f32x4 acc[8];
#pragma unroll
    for (int t = 0; t < 8; ++t) {
        float bv = b[t * 16 + (l & 15)];
        acc[t] = f32x4{bv, bv, bv, bv};
    }

    const s16x8* wp = (const s16x8*)Wp;
#pragma unroll
    for (int s = 0; s < 8; ++s) {
        s16x8 af = (s16x8)0;
        if (rowok) {
            float4 lo = *(const float4*)(xr + s * 32);
            float4 hi = *(const float4*)(xr + s * 32 + 4);
            af[0] = (short)f2bf(lo.x); af[1] = (short)f2bf(lo.y);
            af[2] = (short)f2bf(lo.z); af[3] = (short)f2bf(lo.w);
            af[4] = (short)f2bf(hi.x); af[5] = (short)f2bf(hi.y);
            af[6] = (short)f2bf(hi.z); af[7] = (short)f2bf(hi.w);
        }
#pragma unroll
        for (int t = 0; t < 8; ++t) {
            s16x8 bf = wp[(t * 8 + s) * 64 + l];
            acc[t] = __builtin_amdgcn_mfma_f32_16x16x32_bf16(af, bf, acc[t], 0, 0, 0);
        }
    }

    int crow0 = m0 + (l >> 4) * 4; // C/D: col=lane&15, row=(lane>>4)*4+reg
#pragma unroll
    for (int t = 0; t < 8; ++t) {
        int col = t * 16 + (l & 15);
#pragma unroll
        for (int r = 0; r < 4; ++r) {
            int row = crow0 + r;
            if (row < N_NODES) h[(size_t)row * D_HID + col] = f2bf(acc[t][r]);
        }
    }
}

// ---------------- SpMM: one wave per row; edges u32 (col<<16|bf16val), padded to x8 ----------------

__device__ __forceinline__ void spmm_edges8(const uint* __restrict__ ed, int e,
                                            const uint* __restrict__ srcl, float2& acc) {
    uint ev[8];
#pragma unroll
    for (int i = 0; i < 8; ++i) ev[i] = ed[e + i];
    uint u[8];
#pragma unroll
    for (int i = 0; i < 8; ++i) u[i] = srcl[(ev[i] >> 16) * 64u];
#pragma unroll
    for (int i = 0; i < 8; ++i) {
        float v = __uint_as_float(ev[i] << 16);
        acc.x = fmaf(v, __uint_as_float(u[i] << 16), acc.x);
        acc.y = fmaf(v, __uint_as_float(u[i] & 0xFFFF0000u), acc.y);
    }
}

__device__ __forceinline__ void spmm_row(const int2* __restrict__ rowrange,
                                         const uint* __restrict__ sorted,
                                         int a, int row, int lane,
                                         const uint* __restrict__ src, float2& acc) {
    int2 rr = rowrange[(size_t)a * N_NODES + row];
    int beg = __builtin_amdgcn_readfirstlane(rr.x);
    int end = __builtin_amdgcn_readfirstlane(rr.y);
    const uint* ed = sorted + (size_t)a * NBKT * CAP_S;
    const uint* srcl = src + lane;
    int e = beg;
    for (; e + 16 <= end; e += 16) {
        uint ev[16];
#pragma unroll
        for (int i = 0; i < 16; ++i) ev[i] = ed[e + i];
        uint u[16];
#pragma unroll
        for (int i = 0; i < 16; ++i) u[i] = srcl[(ev[i] >> 16) * 64u];
#pragma unroll
        for (int i = 0; i < 16; ++i) {
            float v = __uint_as_float(ev[i] << 16);
            acc.x = fmaf(v, __uint_as_float(u[i] << 16), acc.x);
            acc.y = fmaf(v, __uint_as_float(u[i] & 0xFFFF0000u), acc.y);
        }
    }
    if (e < end) { // padded length % 16 leaves exactly one 8-batch (or none)
        spmm_edges8(ed, e, srcl, acc);
    }
}

__global__ __launch_bounds__(256) void spmm1_kernel(const int2* __restrict__ rowrange,
                                                    const uint* __restrict__ sorted,
                                                    const int* __restrict__ seq,
                                                    const uint* __restrict__ h,
                                                    ushort* __restrict__ s1) {
    int row = blockIdx.x * 4 + (threadIdx.x >> 6);
    if (row >= N_NODES) return;
    int lane = threadIdx.x & 63;
    float2 acc = {0.f, 0.f};
    spmm_row(rowrange, sorted, seq[0], row, lane, h, acc);
    ushort2 o = {f2bf(acc.x), f2bf(acc.y)};
    *(ushort2*)&s1[(size_t)row * D_HID + 2 * lane] = o;
}

__global__ __launch_bounds__(256) void spmm2_kernel(const int2* __restrict__ rowrange,
                                                    const uint* __restrict__ sorted,
                                                    const int* __restrict__ seq,
                                                    const int* __restrict__ res,
                                                    const uint* __restrict__ s1,
                                                    const uint* __restrict__ h,
                                                    ushort* __restrict__ s2) {
    int row = blockIdx.x * 4 + (threadIdx.x >> 6);
    if (row >= N_NODES) return;
    int lane = threadIdx.x & 63;
    float2 acc = {0.f, 0.f};
    spmm_row(rowrange, sorted, seq[1], row, lane, s1, acc);
    spmm_row(rowrange, sorted, res[0], row, lane, h, acc);
    ushort2 o = {f2bf(acc.x), f2bf(acc.y)};
    *(ushort2*)&s2[(size_t)row * D_HID + 2 * lane] = o;
}

__global__ __launch_bounds__(256) void spmm3_ln_gelu_kernel(const int2* __restrict__ rowrange,
                                                            const uint* __restrict__ sorted,
                                                            const int* __restrict__ seq,
                                                            const int* __restrict__ res,
                                                            const uint* __restrict__ s2,
                                                            const uint* __restrict__ h,
                                                            const uint* __restrict__ s1,
                                                            const float* __restrict__ gamma,
                                                            const float* __restrict__ beta,
                                                            float* __restrict__ out) {
    int row = blockIdx.x * 4 + (threadIdx.x >> 6);
    if (row >= N_NODES) return;
    int lane = threadIdx.x & 63;
    float2 acc = {0.f, 0.f};
    spmm_row(rowrange, sorted, seq[2], row, lane, s2, acc);
    spmm_row(rowrange, sorted, res[1], row, lane, h, acc);
    spmm_row(rowrange, sorted, res[2], row, lane, s1, acc);

    float s = acc.x + acc.y;
    float sq = acc.x * acc.x + acc.y * acc.y;
#pragma unroll
    for (int m = 1; m < 64; m <<= 1) {
        s += __shfl_xor(s, m);
        sq += __shfl_xor(sq, m);
    }
    float mean = s * (1.0f / D_HID);
    float var = fmaxf(sq * (1.0f / D_HID) - mean * mean, 0.f);
    float inv = rsqrtf(var + LN_EPS);
    float2 g = *(const float2*)&gamma[2 * lane];
    float2 bt = *(const float2*)&beta[2 * lane];
    float n0 = (acc.x - mean) * inv * g.x + bt.x;
    float n1 = (acc.y - mean) * inv * g.y + bt.y;
    const float kInvSqrt2 = 0.70710678118654752f;
    float2 o;
    o.x = 0.5f * n0 * (1.f + erff(n0 * kInvSqrt2));
    o.y = 0.5f * n1 * (1.f + erff(n1 * kInvSqrt2));
    *(float2*)&out[(size_t)row * D_HID + 2 * lane] = o;
}

// ---------------- launch ----------------

extern "C" void kernel_launch(void* const* d_in, const int* in_sizes, int n_in,
                              void* d_out, int out_size, void* d_ws, size_t ws_size,
                              hipStream_t stream) {
    const float* x       = (const float*)d_in[0];
    const int*   adjRows = (const int*)d_in[1];
    const int*   adjCols = (const int*)d_in[2];
    const float* adjVals = (const float*)d_in[3];
    const int*   seq     = (const int*)d_in[4];
    const int*   res     = (const int*)d_in[5];
    const float* W       = (const float*)d_in[6];
    const float* b       = (const float*)d_in[7];
    const float* gamma   = (const float*)d_in[8];
    const float* beta    = (const float*)d_in[9];
    float* out = (float*)d_out;

    if (ws_size < WS_TOTAL) return;

    char* ws = (char*)d_ws;
    int*    used     = (int*)(ws + USED_OFF);
    int*    gcur     = (int*)(ws + GCUR_OFF);
    int2*   rowrange = (int2*)(ws + RR_OFF);
    uint*   bedge    = (uint*)(ws + BE_OFF);
    ushort* brow     = (ushort*)(ws + BR_OFF);
    uint*   sorted   = (uint*)(ws + SO_OFF);
    ushort* Wp       = (ushort*)(ws + WP_OFF);
    ushort* h        = (ushort*)(ws + H_OFF);
    ushort* s1       = (ushort*)(ws + S1_OFF);
    ushort* s2       = (ushort*)(ws + S2_OFF);

    packw_kernel<<<16, 256, 0, stream>>>(W, Wp);
    gemm_mfma_kernel<<<(N_NODES + 63) / 64, 256, 0, stream>>>(x, Wp, b, h);

    used_kernel<<<1, 1024, 0, stream>>>(seq, res, used, gcur);
    bscatter_kernel<<<N_ADJ * BPA, BLK, 0, stream>>>(adjRows, adjCols, adjVals, used,
                                                     gcur, bedge, brow);
    bsort_kernel<<<N_ADJ * NBKT, 512, 0, stream>>>(used, gcur, bedge, brow, sorted, rowrange);

    spmm1_kernel<<<(N_NODES + 3) / 4, 256, 0, stream>>>(rowrange, sorted, seq, (const uint*)h, s1);
    spmm2_kernel<<<(N_NODES + 3) / 4, 256, 0, stream>>>(rowrange, sorted, seq, res,
                                                        (const uint*)s1, (const uint*)h, s2);
    spmm3_ln_gelu_kernel<<<(N_NODES + 3) / 4, 256, 0, stream>>>(rowrange, sorted, seq, res,
                                                                (const uint*)s2, (const uint*)h,
                                                                (const uint*)s1, gamma, beta, out);
}

// Round 7
// 255.385 us; speedup vs baseline: 3.6835x; 1.0144x over previous
//
#include <hip/hip_runtime.h>

#define N_NODES 50000
#define N_ADJ 6
#define NNZ 800000
#define D_PREV 256
#define D_HID 128
#define LN_EPS 1e-5f

typedef unsigned int uint;
typedef unsigned short ushort;

typedef short s16x8 __attribute__((ext_vector_type(8)));
typedef float f32x4 __attribute__((ext_vector_type(4)));

static constexpr int BLK = 256;
static constexpr int EPT = 16;
static constexpr int BPA = (NNZ + BLK * EPT - 1) / (BLK * EPT); // 196

static constexpr int BKT_SHIFT = 9;
static constexpr int BKT_ROWS = 1 << BKT_SHIFT;                       // 512
static constexpr int NBKT = (N_NODES + BKT_ROWS - 1) / BKT_ROWS;      // 98

// Bucket counts ~ Binomial(800k, 512/50000): mean 8192, sigma ~90.
static constexpr int CAP_B = 9216;   // mean + 11 sigma (overflow clamped -> loud failure)
static constexpr int CAP_S = 13312;  // CAP_B + max pad (512 rows * 7) + margin

static constexpr size_t WP_ELEMS = 8 * 8 * 64 * 8; // 32768 bf16 of W

static constexpr size_t align256(size_t x) { return (x + 255) & ~(size_t)255; }
static constexpr size_t USED_OFF = 0;
static constexpr size_t GCUR_OFF = align256(USED_OFF + N_ADJ * sizeof(int));
static constexpr size_t RR_OFF   = align256(GCUR_OFF + (size_t)N_ADJ * NBKT * sizeof(int));
static constexpr size_t BE_OFF   = align256(RR_OFF + (size_t)N_ADJ * N_NODES * sizeof(int2));
static constexpr size_t BR_OFF   = align256(BE_OFF + (size_t)N_ADJ * NBKT * CAP_B * sizeof(uint));
static constexpr size_t SO_OFF   = align256(BR_OFF + (size_t)N_ADJ * NBKT * CAP_B * sizeof(ushort));
static constexpr size_t WP_OFF   = align256(SO_OFF + (size_t)N_ADJ * NBKT * CAP_S * sizeof(uint));
static constexpr size_t H_OFF    = align256(WP_OFF + WP_ELEMS * sizeof(ushort));
static constexpr size_t S1_OFF   = align256(H_OFF + (size_t)N_NODES * D_HID * sizeof(ushort));
static constexpr size_t S2_OFF   = align256(S1_OFF + (size_t)N_NODES * D_HID * sizeof(ushort));
static constexpr size_t WS_TOTAL = S2_OFF + (size_t)N_NODES * D_HID * sizeof(ushort);

__device__ __forceinline__ ushort f2bf(float f) {
    uint u = __float_as_uint(f);
    uint r = (u + 0x7FFFu + ((u >> 16) & 1u)) >> 16;
    return (ushort)r;
}

// ---------------- preprocessing ----------------

// used flags + zero bucket cursors (replaces memsetAsync)
__global__ __launch_bounds__(1024) void used_kernel(const int* __restrict__ seq,
                                                    const int* __restrict__ res,
                                                    int* __restrict__ used,
                                                    int* __restrict__ gcur) {
    int t = threadIdx.x;
    if (t < N_ADJ) used[t] = 0;
    for (int i = t; i < N_ADJ * NBKT; i += 1024) gcur[i] = 0;
    __syncthreads();
    if (t == 0) {
        for (int i = 0; i < 3; ++i) used[seq[i]] = 1;
        for (int i = 0; i < 3; ++i) used[res[i]] = 1;
    }
}

// Level 1: scatter edges into fixed-capacity coarse buckets.
// Single reservation for 16 edges/thread -> 42-edge contiguous runs per bucket per block.
__global__ __launch_bounds__(BLK) void bscatter_kernel(const int* __restrict__ rows,
                                                       const int* __restrict__ cols,
                                                       const float* __restrict__ vals,
                                                       const int* __restrict__ used,
                                                       int* __restrict__ gcur,
                                                       uint* __restrict__ bedge,
                                                       ushort* __restrict__ brow) {
    int a = blockIdx.x / BPA;
    if (!used[a]) return;
    __shared__ int lcnt[NBKT];
    __shared__ int lbase[NBKT];
    int t = threadIdx.x;
    if (t < NBKT) lcnt[t] = 0;
    __syncthreads();
    int base = (blockIdx.x % BPA) * (BLK * EPT) + t;
    const int* rr = rows + (size_t)a * NNZ;
    const int* cc = cols + (size_t)a * NNZ;
    const float* vv = vals + (size_t)a * NNZ;
    int erow[EPT], ernk[EPT];
    uint eg[EPT];
#pragma unroll
    for (int i = 0; i < EPT; ++i) {
        int e = base + i * BLK;
        erow[i] = -1;
        if (e < NNZ) {
            int row = rr[e];
            erow[i] = row;
            eg[i] = ((uint)cc[e] << 16) | (uint)f2bf(vv[e]);
            ernk[i] = atomicAdd(&lcnt[row >> BKT_SHIFT], 1);
        }
    }
    __syncthreads();
    if (t < NBKT) lbase[t] = atomicAdd(&gcur[a * NBKT + t], lcnt[t]);
    __syncthreads();
    uint* be = bedge + (size_t)a * NBKT * CAP_B;
    ushort* br = brow + (size_t)a * NBKT * CAP_B;
#pragma unroll
    for (int i = 0; i < EPT; ++i) {
        if (erow[i] >= 0) {
            int bk = erow[i] >> BKT_SHIFT;
            int pos = lbase[bk] + ernk[i];
            if (pos < CAP_B) { // overflow guard (loud failure via validation)
                size_t slot = (size_t)bk * CAP_B + pos;
                be[slot] = eg[i];
                br[slot] = (ushort)(erow[i] & (BKT_ROWS - 1));
            }
        }
    }
}

// Level 2: per-bucket counting sort with per-row pad-to-8 (null edges).
// rowrange[row] = {beg, beg+padded} absolute into sorted (bucket-strided CAP_S).
__global__ __launch_bounds__(512) void bsort_kernel(const int* __restrict__ used,
                                                    const int* __restrict__ gcur,
                                                    const uint* __restrict__ bedge,
                                                    const ushort* __restrict__ brow,
                                                    uint* __restrict__ sorted,
                                                    int2* __restrict__ rowrange) {
    int a = blockIdx.x / NBKT;
    if (!used[a]) return;
    int b = blockIdx.x % NBKT;
    int cnt = gcur[a * NBKT + b];
    if (cnt > CAP_B) cnt = CAP_B;
    int t = threadIdx.x;

    __shared__ int sm[BKT_ROWS];
    __shared__ int cur[BKT_ROWS];
    __shared__ int wsum[8];
    sm[t] = 0;
    __syncthreads();

    const uint* be = bedge + (size_t)a * NBKT * CAP_B + (size_t)b * CAP_B;
    const ushort* br = brow + (size_t)a * NBKT * CAP_B + (size_t)b * CAP_B;
    const uint* br2 = (const uint*)br;
    const uint2* be2 = (const uint2*)be;
    int half = cnt >> 1;
    for (int i = t; i < half; i += 512) {
        uint v = br2[i];
        atomicAdd(&sm[v & 0xFFFFu], 1);
        atomicAdd(&sm[v >> 16], 1);
    }
    if ((cnt & 1) && t == 0) atomicAdd(&sm[br[cnt - 1]], 1);
    __syncthreads();

    int own = sm[t];
    int pad = (own + 7) & ~7;
    // wave-structured exclusive scan of pad
    int lane = t & 63, w = t >> 6;
    int v = pad;
#pragma unroll
    for (int o = 1; o < 64; o <<= 1) {
        int u = __shfl_up(v, o);
        if (lane >= o) v += u;
    }
    if (lane == 63) wsum[w] = v;
    __syncthreads();
    int woff = 0;
#pragma unroll
    for (int k = 0; k < 8; ++k)
        if (k < w) woff += wsum[k];
    int excl = woff + v - pad;

    int row = b * BKT_ROWS + t;
    int sbase = b * CAP_S;
    if (row < N_NODES)
        rowrange[(size_t)a * N_NODES + row] = int2{sbase + excl, sbase + excl + pad};
    cur[t] = excl;
    __syncthreads();

    uint* so = sorted + (size_t)a * NBKT * CAP_S;
    for (int i = t; i < half; i += 512) {
        uint2 e2 = be2[i];
        uint vv = br2[i];
        int p0 = atomicAdd(&cur[vv & 0xFFFFu], 1);
        so[sbase + p0] = e2.x;
        int p1 = atomicAdd(&cur[vv >> 16], 1);
        so[sbase + p1] = e2.y;
    }
    if ((cnt & 1) && t == 0) {
        int r = br[cnt - 1];
        int p = atomicAdd(&cur[r], 1);
        so[sbase + p] = be[cnt - 1];
    }
    __syncthreads();
    // fill pad slots with null edges (col 0, val 0): disjoint from scatter slots
    for (int p = own; p < pad; ++p) so[sbase + excl + p] = 0u;
}

// ---------------- W pack: f32 [256][128] -> bf16 B-fragment order ----------------

__global__ __launch_bounds__(256) void packw_kernel(const float* __restrict__ W,
                                                    ushort* __restrict__ Wp) {
    int gid = blockIdx.x * 256 + threadIdx.x; // (t,s,l)
    int l = gid & 63;
    int ts = gid >> 6;
    int s = ts & 7, t = ts >> 3;
    int kb = s * 32 + (l >> 4) * 8;
    int n = t * 16 + (l & 15);
    ushort* o = Wp + (size_t)gid * 8;
#pragma unroll
    for (int j = 0; j < 8; ++j) o[j] = f2bf(W[(size_t)(kb + j) * D_HID + n]);
}

// ---------------- GEMM: h = bf16(x) @ bf16(W) + b via MFMA ----------------

__global__ __launch_bounds__(256) void gemm_mfma_kernel(const float* __restrict__ x,
                                                        const ushort* __restrict__ Wp,
                                                        const float* __restrict__ b,
                                                        ushort* __restrict__ h) {
    int tid = threadIdx.x;
    int w = tid >> 6, l = tid & 63;
    int m0 = blockIdx.x * 64 + w * 16;
    int arow = m0 + (l & 15);
    bool rowok = arow < N_NODES;
    const float* xr = x + (size_t)arow * D_PREV + (l >> 4) * 8;

    f32x4 acc[8];
#pragma unroll
    for (int t = 0; t < 8; ++t) {
        float bv = b[t * 16 + (l & 15)];
        acc[t] = f32x4{bv, bv, bv, bv};
    }

    const s16x8* wp = (const s16x8*)Wp;
#pragma unroll
    for (int s = 0; s < 8; ++s) {
        s16x8 af = (s16x8)0;
        if (rowok) {
            float4 lo = *(const float4*)(xr + s * 32);
            float4 hi = *(const float4*)(xr + s * 32 + 4);
            af[0] = (short)f2bf(lo.x); af[1] = (short)f2bf(lo.y);
            af[2] = (short)f2bf(lo.z); af[3] = (short)f2bf(lo.w);
            af[4] = (short)f2bf(hi.x); af[5] = (short)f2bf(hi.y);
            af[6] = (short)f2bf(hi.z); af[7] = (short)f2bf(hi.w);
        }
#pragma unroll
        for (int t = 0; t < 8; ++t) {
            s16x8 bf = wp[(t * 8 + s) * 64 + l];
            acc[t] = __builtin_amdgcn_mfma_f32_16x16x32_bf16(af, bf, acc[t], 0, 0, 0);
        }
    }

    int crow0 = m0 + (l >> 4) * 4; // C/D: col=lane&15, row=(lane>>4)*4+reg
#pragma unroll
    for (int t = 0; t < 8; ++t) {
        int col = t * 16 + (l & 15);
#pragma unroll
        for (int r = 0; r < 4; ++r) {
            int row = crow0 + r;
            if (row < N_NODES) h[(size_t)row * D_HID + col] = f2bf(acc[t][r]);
        }
    }
}

// ---------------- SpMM: one wave per row; edges u32 (col<<16|bf16val), padded to x8 ----------------

template <int NB>
__device__ __forceinline__ void spmm_batch(const uint* __restrict__ ed, int e,
                                           const uint* __restrict__ srcl, float2& acc) {
    uint ev[NB];
#pragma unroll
    for (int i = 0; i < NB; ++i) ev[i] = ed[e + i];
    uint u[NB];
#pragma unroll
    for (int i = 0; i < NB; ++i) u[i] = srcl[(ev[i] >> 16) * 64u];
#pragma unroll
    for (int i = 0; i < NB; ++i) {
        float v = __uint_as_float(ev[i] << 16);
        acc.x = fmaf(v, __uint_as_float(u[i] << 16), acc.x);
        acc.y = fmaf(v, __uint_as_float(u[i] & 0xFFFF0000u), acc.y);
    }
}

__device__ __forceinline__ void spmm_row(const int2* __restrict__ rowrange,
                                         const uint* __restrict__ sorted,
                                         int a, int row, int lane,
                                         const uint* __restrict__ src, float2& acc) {
    int2 rr = rowrange[(size_t)a * N_NODES + row];
    int beg = __builtin_amdgcn_readfirstlane(rr.x);
    int end = __builtin_amdgcn_readfirstlane(rr.y);
    const uint* ed = sorted + (size_t)a * NBKT * CAP_S;
    const uint* srcl = src + lane;
    int e = beg;
    for (; e + 32 <= end; e += 32) spmm_batch<32>(ed, e, srcl, acc);
    if (e + 16 <= end) { spmm_batch<16>(ed, e, srcl, acc); e += 16; }
    if (e < end) spmm_batch<8>(ed, e, srcl, acc); // pad-to-8 guarantees exact
}

__global__ __launch_bounds__(256) void spmm1_kernel(const int2* __restrict__ rowrange,
                                                    const uint* __restrict__ sorted,
                                                    const int* __restrict__ seq,
                                                    const uint* __restrict__ h,
                                                    ushort* __restrict__ s1) {
    int row = blockIdx.x * 4 + (threadIdx.x >> 6);
    if (row >= N_NODES) return;
    int lane = threadIdx.x & 63;
    float2 acc = {0.f, 0.f};
    spmm_row(rowrange, sorted, seq[0], row, lane, h, acc);
    ushort2 o = {f2bf(acc.x), f2bf(acc.y)};
    *(ushort2*)&s1[(size_t)row * D_HID + 2 * lane] = o;
}

__global__ __launch_bounds__(256) void spmm2_kernel(const int2* __restrict__ rowrange,
                                                    const uint* __restrict__ sorted,
                                                    const int* __restrict__ seq,
                                                    const int* __restrict__ res,
                                                    const uint* __restrict__ s1,
                                                    const uint* __restrict__ h,
                                                    ushort* __restrict__ s2) {
    int row = blockIdx.x * 4 + (threadIdx.x >> 6);
    if (row >= N_NODES) return;
    int lane = threadIdx.x & 63;
    float2 acc = {0.f, 0.f};
    spmm_row(rowrange, sorted, seq[1], row, lane, s1, acc);
    spmm_row(rowrange, sorted, res[0], row, lane, h, acc);
    ushort2 o = {f2bf(acc.x), f2bf(acc.y)};
    *(ushort2*)&s2[(size_t)row * D_HID + 2 * lane] = o;
}

__global__ __launch_bounds__(256) void spmm3_ln_gelu_kernel(const int2* __restrict__ rowrange,
                                                            const uint* __restrict__ sorted,
                                                            const int* __restrict__ seq,
                                                            const int* __restrict__ res,
                                                            const uint* __restrict__ s2,
                                                            const uint* __restrict__ h,
                                                            const uint* __restrict__ s1,
                                                            const float* __restrict__ gamma,
                                                            const float* __restrict__ beta,
                                                            float* __restrict__ out) {
    int row = blockIdx.x * 4 + (threadIdx.x >> 6);
    if (row >= N_NODES) return;
    int lane = threadIdx.x & 63;
    float2 acc = {0.f, 0.f};
    spmm_row(rowrange, sorted, seq[2], row, lane, s2, acc);
    spmm_row(rowrange, sorted, res[1], row, lane, h, acc);
    spmm_row(rowrange, sorted, res[2], row, lane, s1, acc);

    float s = acc.x + acc.y;
    float sq = acc.x * acc.x + acc.y * acc.y;
#pragma unroll
    for (int m = 1; m < 64; m <<= 1) {
        s += __shfl_xor(s, m);
        sq += __shfl_xor(sq, m);
    }
    float mean = s * (1.0f / D_HID);
    float var = fmaxf(sq * (1.0f / D_HID) - mean * mean, 0.f);
    float inv = rsqrtf(var + LN_EPS);
    float2 g = *(const float2*)&gamma[2 * lane];
    float2 bt = *(const float2*)&beta[2 * lane];
    float n0 = (acc.x - mean) * inv * g.x + bt.x;
    float n1 = (acc.y - mean) * inv * g.y + bt.y;
    const float kInvSqrt2 = 0.70710678118654752f;
    float2 o;
    o.x = 0.5f * n0 * (1.f + erff(n0 * kInvSqrt2));
    o.y = 0.5f * n1 * (1.f + erff(n1 * kInvSqrt2));
    *(float2*)&out[(size_t)row * D_HID + 2 * lane] = o;
}

// ---------------- launch ----------------

extern "C" void kernel_launch(void* const* d_in, const int* in_sizes, int n_in,
                              void* d_out, int out_size, void* d_ws, size_t ws_size,
                              hipStream_t stream) {
    const float* x       = (const float*)d_in[0];
    const int*   adjRows = (const int*)d_in[1];
    const int*   adjCols = (const int*)d_in[2];
    const float* adjVals = (const float*)d_in[3];
    const int*   seq     = (const int*)d_in[4];
    const int*   res     = (const int*)d_in[5];
    const float* W       = (const float*)d_in[6];
    const float* b       = (const float*)d_in[7];
    const float* gamma   = (const float*)d_in[8];
    const float* beta    = (const float*)d_in[9];
    float* out = (float*)d_out;

    if (ws_size < WS_TOTAL) return;

    char* ws = (char*)d_ws;
    int*    used     = (int*)(ws + USED_OFF);
    int*    gcur     = (int*)(ws + GCUR_OFF);
    int2*   rowrange = (int2*)(ws + RR_OFF);
    uint*   bedge    = (uint*)(ws + BE_OFF);
    ushort* brow     = (ushort*)(ws + BR_OFF);
    uint*   sorted   = (uint*)(ws + SO_OFF);
    ushort* Wp       = (ushort*)(ws + WP_OFF);
    ushort* h        = (ushort*)(ws + H_OFF);
    ushort* s1       = (ushort*)(ws + S1_OFF);
    ushort* s2       = (ushort*)(ws + S2_OFF);

    packw_kernel<<<16, 256, 0, stream>>>(W, Wp);
    gemm_mfma_kernel<<<(N_NODES + 63) / 64, 256, 0, stream>>>(x, Wp, b, h);

    used_kernel<<<1, 1024, 0, stream>>>(seq, res, used, gcur);
    bscatter_kernel<<<N_ADJ * BPA, BLK, 0, stream>>>(adjRows, adjCols, adjVals, used,
                                                     gcur, bedge, brow);
    bsort_kernel<<<N_ADJ * NBKT, 512, 0, stream>>>(used, gcur, bedge, brow, sorted, rowrange);

    spmm1_kernel<<<(N_NODES + 3) / 4, 256, 0, stream>>>(rowrange, sorted, seq, (const uint*)h, s1);
    spmm2_kernel<<<(N_NODES + 3) / 4, 256, 0, stream>>>(rowrange, sorted, seq, res,
                                                        (const uint*)s1, (const uint*)h, s2);
    spmm3_ln_gelu_kernel<<<(N_NODES + 3) / 4, 256, 0, stream>>>(rowrange, sorted, seq, res,
                                                                (const uint*)s2, (const uint*)h,
                                                                (const uint*)s1, gamma, beta, out);
}

// Round 8
// 245.030 us; speedup vs baseline: 3.8392x; 1.0423x over previous
//
#include <hip/hip_runtime.h>

#define N_NODES 50000
#define N_ADJ 6
#define NNZ 800000
#define D_PREV 256
#define D_HID 128
#define LN_EPS 1e-5f

typedef unsigned int uint;
typedef unsigned short ushort;

typedef short s16x8 __attribute__((ext_vector_type(8)));
typedef float f32x4 __attribute__((ext_vector_type(4)));

static constexpr int BLK = 256;
static constexpr int EPT = 16;
static constexpr int BPA = (NNZ + BLK * EPT - 1) / (BLK * EPT); // 196

static constexpr int BKT_SHIFT = 9;
static constexpr int BKT_ROWS = 1 << BKT_SHIFT;                       // 512
static constexpr int NBKT = (N_NODES + BKT_ROWS - 1) / BKT_ROWS;      // 98

// Bucket counts ~ Binomial(800k, 512/50000): mean 8192, sigma ~90.
static constexpr int CAP_B = 9216;   // mean + 11 sigma (overflow clamped -> loud failure)
static constexpr int CAP_S = 13312;  // CAP_B + max pad (512 rows * 7) + margin

static constexpr size_t WP_ELEMS = 8 * 8 * 64 * 8; // 32768 bf16 of W

static constexpr size_t align256(size_t x) { return (x + 255) & ~(size_t)255; }
static constexpr size_t USED_OFF = 0;
static constexpr size_t GCUR_OFF = align256(USED_OFF + N_ADJ * sizeof(int));
static constexpr size_t RR_OFF   = align256(GCUR_OFF + (size_t)N_ADJ * NBKT * sizeof(int));
static constexpr size_t BE_OFF   = align256(RR_OFF + (size_t)N_ADJ * N_NODES * sizeof(int2));
static constexpr size_t SO_OFF   = align256(BE_OFF + (size_t)N_ADJ * NBKT * CAP_B * sizeof(uint2));
static constexpr size_t WP_OFF   = align256(SO_OFF + (size_t)N_ADJ * NBKT * CAP_S * sizeof(uint));
static constexpr size_t H_OFF    = align256(WP_OFF + WP_ELEMS * sizeof(ushort));
static constexpr size_t S1_OFF   = align256(H_OFF + (size_t)N_NODES * D_HID * sizeof(ushort));
static constexpr size_t S2_OFF   = align256(S1_OFF + (size_t)N_NODES * D_HID * sizeof(ushort));
static constexpr size_t WS_TOTAL = S2_OFF + (size_t)N_NODES * D_HID * sizeof(ushort);

__device__ __forceinline__ ushort f2bf(float f) {
    uint u = __float_as_uint(f);
    uint r = (u + 0x7FFFu + ((u >> 16) & 1u)) >> 16;
    return (ushort)r;
}

// ---------------- preprocessing ----------------

// used flags + zero bucket cursors (replaces memsetAsync)
__global__ __launch_bounds__(1024) void used_kernel(const int* __restrict__ seq,
                                                    const int* __restrict__ res,
                                                    int* __restrict__ used,
                                                    int* __restrict__ gcur) {
    int t = threadIdx.x;
    if (t < N_ADJ) used[t] = 0;
    for (int i = t; i < N_ADJ * NBKT; i += 1024) gcur[i] = 0;
    __syncthreads();
    if (t == 0) {
        for (int i = 0; i < 3; ++i) used[seq[i]] = 1;
        for (int i = 0; i < 3; ++i) used[res[i]] = 1;
    }
}

// Level 1: scatter edges into fixed-capacity coarse buckets.
// Packed uint2 {col<<16|bf16val, localrow}: one write stream, 336B runs/bucket/block.
__global__ __launch_bounds__(BLK) void bscatter_kernel(const int* __restrict__ rows,
                                                       const int* __restrict__ cols,
                                                       const float* __restrict__ vals,
                                                       const int* __restrict__ used,
                                                       int* __restrict__ gcur,
                                                       uint2* __restrict__ bedge) {
    int a = blockIdx.x / BPA;
    if (!used[a]) return;
    __shared__ int lcnt[NBKT];
    __shared__ int lbase[NBKT];
    int t = threadIdx.x;
    if (t < NBKT) lcnt[t] = 0;
    __syncthreads();
    int base = (blockIdx.x % BPA) * (BLK * EPT) + t;
    const int* rr = rows + (size_t)a * NNZ;
    const int* cc = cols + (size_t)a * NNZ;
    const float* vv = vals + (size_t)a * NNZ;
    int erow[EPT], ernk[EPT];
    uint eg[EPT];
#pragma unroll
    for (int i = 0; i < EPT; ++i) {
        int e = base + i * BLK;
        erow[i] = -1;
        if (e < NNZ) {
            int row = rr[e];
            erow[i] = row;
            eg[i] = ((uint)cc[e] << 16) | (uint)f2bf(vv[e]);
            ernk[i] = atomicAdd(&lcnt[row >> BKT_SHIFT], 1);
        }
    }
    __syncthreads();
    if (t < NBKT) lbase[t] = atomicAdd(&gcur[a * NBKT + t], lcnt[t]);
    __syncthreads();
    uint2* be = bedge + (size_t)a * NBKT * CAP_B;
#pragma unroll
    for (int i = 0; i < EPT; ++i) {
        if (erow[i] >= 0) {
            int bk = erow[i] >> BKT_SHIFT;
            int pos = lbase[bk] + ernk[i];
            if (pos < CAP_B) { // overflow guard (loud failure via validation)
                be[(size_t)bk * CAP_B + pos] =
                    uint2{eg[i], (uint)(erow[i] & (BKT_ROWS - 1))};
            }
        }
    }
}

// Level 2: per-bucket counting sort, bucket fully staged in LDS (~55KB).
// One coalesced global read; hist + scatter run from LDS.
// rowrange[row] = {beg, beg+padded} absolute into sorted (bucket-strided CAP_S).
__global__ __launch_bounds__(512) void bsort_kernel(const int* __restrict__ used,
                                                    const int* __restrict__ gcur,
                                                    const uint2* __restrict__ bedge,
                                                    uint* __restrict__ sorted,
                                                    int2* __restrict__ rowrange) {
    int a = blockIdx.x / NBKT;
    if (!used[a]) return;
    int b = blockIdx.x % NBKT;
    int cnt = gcur[a * NBKT + b];
    if (cnt > CAP_B) cnt = CAP_B;
    int t = threadIdx.x;

    __shared__ uint   lcol[CAP_B];   // 36.9 KB
    __shared__ ushort lrow[CAP_B];   // 18.4 KB
    __shared__ int sm[BKT_ROWS];
    __shared__ int cur[BKT_ROWS];
    __shared__ int wsum[8];
    sm[t] = 0;
    __syncthreads();

    const uint2* be = bedge + (size_t)a * NBKT * CAP_B + (size_t)b * CAP_B;
    for (int i = t; i < cnt; i += 512) {
        uint2 e = be[i];
        lcol[i] = e.x;
        lrow[i] = (ushort)e.y;
        atomicAdd(&sm[e.y], 1);
    }
    __syncthreads();

    int own = sm[t];
    int pad = (own + 7) & ~7;
    // wave-structured exclusive scan of pad
    int lane = t & 63, w = t >> 6;
    int v = pad;
#pragma unroll
    for (int o = 1; o < 64; o <<= 1) {
        int u = __shfl_up(v, o);
        if (lane >= o) v += u;
    }
    if (lane == 63) wsum[w] = v;
    __syncthreads();
    int woff = 0;
#pragma unroll
    for (int k = 0; k < 8; ++k)
        if (k < w) woff += wsum[k];
    int excl = woff + v - pad;

    int row = b * BKT_ROWS + t;
    int sbase = b * CAP_S;
    if (row < N_NODES)
        rowrange[(size_t)a * N_NODES + row] = int2{sbase + excl, sbase + excl + pad};
    cur[t] = excl;
    __syncthreads();

    uint* so = sorted + (size_t)a * NBKT * CAP_S;
    for (int i = t; i < cnt; i += 512) {
        int r = lrow[i];
        int p = atomicAdd(&cur[r], 1);
        so[sbase + p] = lcol[i];
    }
    // fill pad slots with null edges (col 0, val 0): disjoint from scatter slots
    for (int p = own; p < pad; ++p) so[sbase + excl + p] = 0u;
}

// ---------------- W pack: f32 [256][128] -> bf16 B-fragment order ----------------

__global__ __launch_bounds__(256) void packw_kernel(const float* __restrict__ W,
                                                    ushort* __restrict__ Wp) {
    int gid = blockIdx.x * 256 + threadIdx.x; // (t,s,l)
    int l = gid & 63;
    int ts = gid >> 6;
    int s = ts & 7, t = ts >> 3;
    int kb = s * 32 + (l >> 4) * 8;
    int n = t * 16 + (l & 15);
    ushort* o = Wp + (size_t)gid * 8;
#pragma unroll
    for (int j = 0; j < 8; ++j) o[j] = f2bf(W[(size_t)(kb + j) * D_HID + n]);
}

// ---------------- GEMM: h = bf16(x) @ bf16(W) + b via MFMA ----------------

__global__ __launch_bounds__(256) void gemm_mfma_kernel(const float* __restrict__ x,
                                                        const ushort* __restrict__ Wp,
                                                        const float* __restrict__ b,
                                                        ushort* __restrict__ h) {
    int tid = threadIdx.x;
    int w = tid >> 6, l = tid & 63;
    int m0 = blockIdx.x * 64 + w * 16;
    int arow = m0 + (l & 15);
    bool rowok = arow < N_NODES;
    const float* xr = x + (size_t)arow * D_PREV + (l >> 4) * 8;

    f32x4 acc[8];
#pragma unroll
    for (int t = 0; t < 8; ++t) {
        float bv = b[t * 16 + (l & 15)];
        acc[t] = f32x4{bv, bv, bv, bv};
    }

    const s16x8* wp = (const s16x8*)Wp;
#pragma unroll
    for (int s = 0; s < 8; ++s) {
        s16x8 af = (s16x8)0;
        if (rowok) {
            float4 lo = *(const float4*)(xr + s * 32);
            float4 hi = *(const float4*)(xr + s * 32 + 4);
            af[0] = (short)f2bf(lo.x); af[1] = (short)f2bf(lo.y);
            af[2] = (short)f2bf(lo.z); af[3] = (short)f2bf(lo.w);
            af[4] = (short)f2bf(hi.x); af[5] = (short)f2bf(hi.y);
            af[6] = (short)f2bf(hi.z); af[7] = (short)f2bf(hi.w);
        }
#pragma unroll
        for (int t = 0; t < 8; ++t) {
            s16x8 bf = wp[(t * 8 + s) * 64 + l];
            acc[t] = __builtin_amdgcn_mfma_f32_16x16x32_bf16(af, bf, acc[t], 0, 0, 0);
        }
    }

    int crow0 = m0 + (l >> 4) * 4; // C/D: col=lane&15, row=(lane>>4)*4+reg
#pragma unroll
    for (int t = 0; t < 8; ++t) {
        int col = t * 16 + (l & 15);
#pragma unroll
        for (int r = 0; r < 4; ++r) {
            int row = crow0 + r;
            if (row < N_NODES) h[(size_t)row * D_HID + col] = f2bf(acc[t][r]);
        }
    }
}

// ---------------- SpMM: one wave per row; edges u32 (col<<16|bf16val), padded to x8 ----------------

template <int NB>
__device__ __forceinline__ void spmm_batch(const uint* __restrict__ ed, int e,
                                           const uint* __restrict__ srcl, float2& acc) {
    uint ev[NB];
#pragma unroll
    for (int i = 0; i < NB; ++i) ev[i] = ed[e + i];
    uint u[NB];
#pragma unroll
    for (int i = 0; i < NB; ++i) u[i] = srcl[(ev[i] >> 16) * 64u];
#pragma unroll
    for (int i = 0; i < NB; ++i) {
        float v = __uint_as_float(ev[i] << 16);
        acc.x = fmaf(v, __uint_as_float(u[i] << 16), acc.x);
        acc.y = fmaf(v, __uint_as_float(u[i] & 0xFFFF0000u), acc.y);
    }
}

__device__ __forceinline__ void spmm_row(const int2* __restrict__ rowrange,
                                         const uint* __restrict__ sorted,
                                         int a, int row, int lane,
                                         const uint* __restrict__ src, float2& acc) {
    int2 rr = rowrange[(size_t)a * N_NODES + row];
    int beg = __builtin_amdgcn_readfirstlane(rr.x);
    int end = __builtin_amdgcn_readfirstlane(rr.y);
    const uint* ed = sorted + (size_t)a * NBKT * CAP_S;
    const uint* srcl = src + lane;
    int e = beg;
    for (; e + 32 <= end; e += 32) spmm_batch<32>(ed, e, srcl, acc);
    if (e + 16 <= end) { spmm_batch<16>(ed, e, srcl, acc); e += 16; }
    if (e < end) spmm_batch<8>(ed, e, srcl, acc); // pad-to-8 guarantees exact
}

__global__ __launch_bounds__(256) void spmm1_kernel(const int2* __restrict__ rowrange,
                                                    const uint* __restrict__ sorted,
                                                    const int* __restrict__ seq,
                                                    const uint* __restrict__ h,
                                                    ushort* __restrict__ s1) {
    int row = blockIdx.x * 4 + (threadIdx.x >> 6);
    if (row >= N_NODES) return;
    int lane = threadIdx.x & 63;
    float2 acc = {0.f, 0.f};
    spmm_row(rowrange, sorted, seq[0], row, lane, h, acc);
    ushort2 o = {f2bf(acc.x), f2bf(acc.y)};
    *(ushort2*)&s1[(size_t)row * D_HID + 2 * lane] = o;
}

__global__ __launch_bounds__(256) void spmm2_kernel(const int2* __restrict__ rowrange,
                                                    const uint* __restrict__ sorted,
                                                    const int* __restrict__ seq,
                                                    const int* __restrict__ res,
                                                    const uint* __restrict__ s1,
                                                    const uint* __restrict__ h,
                                                    ushort* __restrict__ s2) {
    int row = blockIdx.x * 4 + (threadIdx.x >> 6);
    if (row >= N_NODES) return;
    int lane = threadIdx.x & 63;
    float2 acc = {0.f, 0.f};
    spmm_row(rowrange, sorted, seq[1], row, lane, s1, acc);
    spmm_row(rowrange, sorted, res[0], row, lane, h, acc);
    ushort2 o = {f2bf(acc.x), f2bf(acc.y)};
    *(ushort2*)&s2[(size_t)row * D_HID + 2 * lane] = o;
}

__global__ __launch_bounds__(256) void spmm3_ln_gelu_kernel(const int2* __restrict__ rowrange,
                                                            const uint* __restrict__ sorted,
                                                            const int* __restrict__ seq,
                                                            const int* __restrict__ res,
                                                            const uint* __restrict__ s2,
                                                            const uint* __restrict__ h,
                                                            const uint* __restrict__ s1,
                                                            const float* __restrict__ gamma,
                                                            const float* __restrict__ beta,
                                                            float* __restrict__ out) {
    int row = blockIdx.x * 4 + (threadIdx.x >> 6);
    if (row >= N_NODES) return;
    int lane = threadIdx.x & 63;
    float2 acc = {0.f, 0.f};
    spmm_row(rowrange, sorted, seq[2], row, lane, s2, acc);
    spmm_row(rowrange, sorted, res[1], row, lane, h, acc);
    spmm_row(rowrange, sorted, res[2], row, lane, s1, acc);

    float s = acc.x + acc.y;
    float sq = acc.x * acc.x + acc.y * acc.y;
#pragma unroll
    for (int m = 1; m < 64; m <<= 1) {
        s += __shfl_xor(s, m);
        sq += __shfl_xor(sq, m);
    }
    float mean = s * (1.0f / D_HID);
    float var = fmaxf(sq * (1.0f / D_HID) - mean * mean, 0.f);
    float inv = rsqrtf(var + LN_EPS);
    float2 g = *(const float2*)&gamma[2 * lane];
    float2 bt = *(const float2*)&beta[2 * lane];
    float n0 = (acc.x - mean) * inv * g.x + bt.x;
    float n1 = (acc.y - mean) * inv * g.y + bt.y;
    const float kInvSqrt2 = 0.70710678118654752f;
    float2 o;
    o.x = 0.5f * n0 * (1.f + erff(n0 * kInvSqrt2));
    o.y = 0.5f * n1 * (1.f + erff(n1 * kInvSqrt2));
    *(float2*)&out[(size_t)row * D_HID + 2 * lane] = o;
}

// ---------------- launch ----------------

extern "C" void kernel_launch(void* const* d_in, const int* in_sizes, int n_in,
                              void* d_out, int out_size, void* d_ws, size_t ws_size,
                              hipStream_t stream) {
    const float* x       = (const float*)d_in[0];
    const int*   adjRows = (const int*)d_in[1];
    const int*   adjCols = (const int*)d_in[2];
    const float* adjVals = (const float*)d_in[3];
    const int*   seq     = (const int*)d_in[4];
    const int*   res     = (const int*)d_in[5];
    const float* W       = (const float*)d_in[6];
    const float* b       = (const float*)d_in[7];
    const float* gamma   = (const float*)d_in[8];
    const float* beta    = (const float*)d_in[9];
    float* out = (float*)d_out;

    if (ws_size < WS_TOTAL) return;

    char* ws = (char*)d_ws;
    int*    used     = (int*)(ws + USED_OFF);
    int*    gcur     = (int*)(ws + GCUR_OFF);
    int2*   rowrange = (int2*)(ws + RR_OFF);
    uint2*  bedge    = (uint2*)(ws + BE_OFF);
    uint*   sorted   = (uint*)(ws + SO_OFF);
    ushort* Wp       = (ushort*)(ws + WP_OFF);
    ushort* h        = (ushort*)(ws + H_OFF);
    ushort* s1       = (ushort*)(ws + S1_OFF);
    ushort* s2       = (ushort*)(ws + S2_OFF);

    packw_kernel<<<16, 256, 0, stream>>>(W, Wp);
    gemm_mfma_kernel<<<(N_NODES + 63) / 64, 256, 0, stream>>>(x, Wp, b, h);

    used_kernel<<<1, 1024, 0, stream>>>(seq, res, used, gcur);
    bscatter_kernel<<<N_ADJ * BPA, BLK, 0, stream>>>(adjRows, adjCols, adjVals, used,
                                                     gcur, bedge);
    bsort_kernel<<<N_ADJ * NBKT, 512, 0, stream>>>(used, gcur, bedge, sorted, rowrange);

    spmm1_kernel<<<(N_NODES + 3) / 4, 256, 0, stream>>>(rowrange, sorted, seq, (const uint*)h, s1);
    spmm2_kernel<<<(N_NODES + 3) / 4, 256, 0, stream>>>(rowrange, sorted, seq, res,
                                                        (const uint*)s1, (const uint*)h, s2);
    spmm3_ln_gelu_kernel<<<(N_NODES + 3) / 4, 256, 0, stream>>>(rowrange, sorted, seq, res,
                                                                (const uint*)s2, (const uint*)h,
                                                                (const uint*)s1, gamma, beta, out);
}